// Round 2
// baseline (1324.372 us; speedup 1.0000x reference)
//
#include <hip/hip_runtime.h>
#include <hip/hip_bf16.h>

// Two-level counting-sort CSR build:
//   bucket = row >> 8  (256 rows per bucket, NBK = ceil(N/256) <= 512 for N <= 131072)
//   packed edge record = (localrow << 17) | col   (needs N <= 2^17)

#define EPB 4096  // edges per block in bucket count/scatter

// ---- Pass A1: per-bucket edge counts ----
__global__ __launch_bounds__(256) void bucket_count(const int* __restrict__ row,
                                                    int* __restrict__ bcnt,
                                                    int e, int nbk) {
    __shared__ int bh[512];
    int tid = threadIdx.x;
    for (int j = tid; j < nbk; j += 256) bh[j] = 0;
    __syncthreads();
    int base = blockIdx.x * EPB;
#pragma unroll
    for (int k = 0; k < EPB / 256; ++k) {
        int i = base + k * 256 + tid;
        if (i < e) atomicAdd(&bh[row[i] >> 8], 1);
    }
    __syncthreads();
    for (int j = tid; j < nbk; j += 256) {
        int c = bh[j];
        if (c) atomicAdd(&bcnt[j], c);
    }
}

// ---- Pass A2: scan bucket counts (single block) ----
__global__ __launch_bounds__(256) void bucket_scan(const int* __restrict__ bcnt,
                                                   int* __restrict__ bbase,
                                                   int* __restrict__ bcursor,
                                                   int* __restrict__ off,
                                                   int nbk, int n, int e) {
    __shared__ int sa[512], sb[512];
    int tid = threadIdx.x;
    for (int j = tid; j < 512; j += 256) sa[j] = (j < nbk) ? bcnt[j] : 0;
    __syncthreads();
    int* in = sa;
    int* out = sb;
    for (int d = 1; d < 512; d <<= 1) {
        for (int j = tid; j < 512; j += 256)
            out[j] = in[j] + ((j >= d) ? in[j - d] : 0);
        __syncthreads();
        int* t = in; in = out; out = t;
    }
    for (int j = tid; j < nbk; j += 256) {
        int incl = in[j];
        int excl = incl - bcnt[j];
        bbase[j] = excl;
        bcursor[j] = excl;
        if (j == nbk - 1) bbase[nbk] = incl;
    }
    if (tid == 0) off[n] = e;
}

// ---- Pass A3: scatter packed edges into bucket regions ----
__global__ __launch_bounds__(256) void bucket_scatter(const int* __restrict__ row,
                                                      const int* __restrict__ col,
                                                      int* __restrict__ bcursor,
                                                      int* __restrict__ packed,
                                                      int e, int nbk) {
    __shared__ int bh[512];
    __shared__ int bbase[512];
    __shared__ int bcur[512];
    int tid = threadIdx.x;
    for (int j = tid; j < nbk; j += 256) { bh[j] = 0; bcur[j] = 0; }
    __syncthreads();
    int base = blockIdx.x * EPB;
#pragma unroll
    for (int k = 0; k < EPB / 256; ++k) {
        int i = base + k * 256 + tid;
        if (i < e) atomicAdd(&bh[row[i] >> 8], 1);
    }
    __syncthreads();
    for (int j = tid; j < nbk; j += 256) {
        int c = bh[j];
        bbase[j] = c ? atomicAdd(&bcursor[j], c) : 0;
    }
    __syncthreads();
#pragma unroll
    for (int k = 0; k < EPB / 256; ++k) {
        int i = base + k * 256 + tid;
        if (i < e) {
            int r = row[i];
            int b = r >> 8;
            int slot = bbase[b] + atomicAdd(&bcur[b], 1);
            packed[slot] = ((r & 255) << 17) | col[i];
        }
    }
}

// ---- Pass B: per-bucket row histogram + scan -> off/dis/csr ----
__global__ __launch_bounds__(256) void bucket_build(const int* __restrict__ packed,
                                                    const int* __restrict__ bbase,
                                                    int* __restrict__ off,
                                                    float* __restrict__ dis,
                                                    int* __restrict__ csr, int n) {
    __shared__ int rcnt[256];
    __shared__ int sa[256], sb[256];
    int tid = threadIdx.x;
    int b = blockIdx.x;
    int ebase = bbase[b], eend = bbase[b + 1];
    rcnt[tid] = 0;
    __syncthreads();
    for (int e = ebase + tid; e < eend; e += 256)
        atomicAdd(&rcnt[packed[e] >> 17], 1);
    __syncthreads();
    sa[tid] = rcnt[tid];
    __syncthreads();
    int* in = sa;
    int* out = sb;
    for (int d = 1; d < 256; d <<= 1) {
        out[tid] = in[tid] + ((tid >= d) ? in[tid - d] : 0);
        __syncthreads();
        int* t = in; in = out; out = t;
    }
    // in[tid] = inclusive scan; out is free for reuse as cursor
    int grow = b * 256 + tid;
    int c = rcnt[tid];
    int excl = in[tid] - c;
    if (grow < n) {
        off[grow] = ebase + excl;
        dis[grow] = (c > 0) ? rsqrtf((float)c) : 0.0f;
    }
    out[tid] = excl;
    __syncthreads();
    for (int e = ebase + tid; e < eend; e += 256) {
        int p = packed[e];
        int lr = p >> 17;
        int pos = atomicAdd(&out[lr], 1);
        csr[ebase + pos] = p & 0x1FFFF;
    }
}

// ---------------- y = dis[i] * x[i][:] ----------------

__global__ __launch_bounds__(256) void scale_y(const float* __restrict__ x,
                                               const float* __restrict__ dis,
                                               float* __restrict__ y, int n) {
    int id = blockIdx.x * 256 + threadIdx.x;  // over N*16 float4s
    if (id < n * 16) {
        int r = id >> 4;
        float d = dis[r];
        float4 v = ((const float4*)x)[id];
        float4 o = {v.x * d, v.y * d, v.z * d, v.w * d};
        ((float4*)y)[id] = o;
    }
}

// ---------------- aggregate: tx[r][f] = -dis[r] * sum_e y[col][f] ----------------
// thread = (row, feature-quad): 16 threads per row, 16 rows per block.

__global__ __launch_bounds__(256) void aggregate(const float* __restrict__ y,
                                                 const int* __restrict__ csr,
                                                 const int* __restrict__ off,
                                                 const float* __restrict__ dis,
                                                 float* __restrict__ tx, int n) {
    int tid = threadIdx.x;
    int r = blockIdx.x * 16 + (tid >> 4);
    if (r >= n) return;
    int q = tid & 15;
    int s0 = off[r], e1 = off[r + 1];
    const float4* Y = (const float4*)y;
    float ax = 0.f, ay = 0.f, az = 0.f, aw = 0.f;
    int t = s0;
    for (; t + 4 <= e1; t += 4) {
        int c0 = csr[t], c1 = csr[t + 1], c2 = csr[t + 2], c3 = csr[t + 3];
        float4 v0 = Y[(size_t)c0 * 16 + q];
        float4 v1 = Y[(size_t)c1 * 16 + q];
        float4 v2 = Y[(size_t)c2 * 16 + q];
        float4 v3 = Y[(size_t)c3 * 16 + q];
        ax += (v0.x + v1.x) + (v2.x + v3.x);
        ay += (v0.y + v1.y) + (v2.y + v3.y);
        az += (v0.z + v1.z) + (v2.z + v3.z);
        aw += (v0.w + v1.w) + (v2.w + v3.w);
    }
    for (; t < e1; ++t) {
        int c = csr[t];
        float4 v = Y[(size_t)c * 16 + q];
        ax += v.x; ay += v.y; az += v.z; aw += v.w;
    }
    float d = -dis[r];
    float4 o = {ax * d, ay * d, az * d, aw * d};
    *(float4*)&tx[(size_t)r * 64 + q * 4] = o;
}

// ---------------- dense: out = act(h@W0 + tx@W1 + b); optionally y = dis*out ----------------
// 2 rows per thread, 32 rows per block.

template <bool RELU, bool WRITE_Y>
__global__ __launch_bounds__(256) void dense64(const float* h_in,
                                               const float* __restrict__ tx,
                                               const float* __restrict__ W0,
                                               const float* __restrict__ W1,
                                               const float* __restrict__ bias,
                                               const float* __restrict__ dis,
                                               float* h_out,
                                               float* __restrict__ y, int n) {
    __shared__ float W0s[64 * 64];
    __shared__ float W1s[64 * 64];
    __shared__ float hs[32][68];
    __shared__ float ts[32][68];
    int tid = threadIdx.x;
    for (int idx = tid; idx < 4096; idx += 256) {
        W0s[idx] = W0[idx];
        W1s[idx] = W1[idx];
    }
    int row0 = blockIdx.x * 32;
    for (int idx = tid; idx < 2048; idx += 256) {
        int rr = idx >> 6, c = idx & 63;
        int r = row0 + rr;
        float hv = 0.f, tv = 0.f;
        if (r < n) {
            hv = h_in[(size_t)r * 64 + c];
            tv = tx[(size_t)r * 64 + c];
        }
        hs[rr][c] = hv;
        ts[rr][c] = tv;
    }
    __syncthreads();
    int jg = (tid & 15) * 4;
    int rr0 = (tid >> 4) * 2;
    float bx0 = bias[jg], bx1 = bias[jg + 1], bx2 = bias[jg + 2], bx3 = bias[jg + 3];
    float a00 = bx0, a01 = bx1, a02 = bx2, a03 = bx3;
    float a10 = bx0, a11 = bx1, a12 = bx2, a13 = bx3;
#pragma unroll
    for (int k = 0; k < 64; ++k) {
        float4 w0 = *(const float4*)&W0s[k * 64 + jg];
        float4 w1 = *(const float4*)&W1s[k * 64 + jg];
        float h0 = hs[rr0][k], t0 = ts[rr0][k];
        float h1 = hs[rr0 + 1][k], t1 = ts[rr0 + 1][k];
        a00 = fmaf(h0, w0.x, fmaf(t0, w1.x, a00));
        a01 = fmaf(h0, w0.y, fmaf(t0, w1.y, a01));
        a02 = fmaf(h0, w0.z, fmaf(t0, w1.z, a02));
        a03 = fmaf(h0, w0.w, fmaf(t0, w1.w, a03));
        a10 = fmaf(h1, w0.x, fmaf(t1, w1.x, a10));
        a11 = fmaf(h1, w0.y, fmaf(t1, w1.y, a11));
        a12 = fmaf(h1, w0.z, fmaf(t1, w1.z, a12));
        a13 = fmaf(h1, w0.w, fmaf(t1, w1.w, a13));
    }
    if (RELU) {
        a00 = fmaxf(a00, 0.f); a01 = fmaxf(a01, 0.f); a02 = fmaxf(a02, 0.f); a03 = fmaxf(a03, 0.f);
        a10 = fmaxf(a10, 0.f); a11 = fmaxf(a11, 0.f); a12 = fmaxf(a12, 0.f); a13 = fmaxf(a13, 0.f);
    }
    int r0 = row0 + rr0;
    if (r0 < n) {
        float4 o = {a00, a01, a02, a03};
        *(float4*)&h_out[(size_t)r0 * 64 + jg] = o;
        if (WRITE_Y) {
            float dv = dis[r0];
            float4 yv = {a00 * dv, a01 * dv, a02 * dv, a03 * dv};
            *(float4*)&y[(size_t)r0 * 64 + jg] = yv;
        }
    }
    if (r0 + 1 < n) {
        float4 o = {a10, a11, a12, a13};
        *(float4*)&h_out[(size_t)(r0 + 1) * 64 + jg] = o;
        if (WRITE_Y) {
            float dv = dis[r0 + 1];
            float4 yv = {a10 * dv, a11 * dv, a12 * dv, a13 * dv};
            *(float4*)&y[(size_t)(r0 + 1) * 64 + jg] = yv;
        }
    }
}

__global__ __launch_bounds__(256) void dense16(const float* __restrict__ h_in,
                                               const float* __restrict__ tx,
                                               const float* __restrict__ W0,
                                               const float* __restrict__ W1,
                                               const float* __restrict__ bias,
                                               float* __restrict__ out, int n) {
    __shared__ float W0s[64 * 16];
    __shared__ float W1s[64 * 16];
    __shared__ float hs[64][68];
    __shared__ float ts[64][68];
    int tid = threadIdx.x;
    for (int idx = tid; idx < 1024; idx += 256) {
        W0s[idx] = W0[idx];
        W1s[idx] = W1[idx];
    }
    int row0 = blockIdx.x * 64;
    for (int idx = tid; idx < 4096; idx += 256) {
        int rr = idx >> 6, c = idx & 63;
        int r = row0 + rr;
        float hv = 0.f, tv = 0.f;
        if (r < n) {
            hv = h_in[(size_t)r * 64 + c];
            tv = tx[(size_t)r * 64 + c];
        }
        hs[rr][c] = hv;
        ts[rr][c] = tv;
    }
    __syncthreads();
    int jg = (tid & 3) * 4;  // column group (16 cols -> 4 groups)
    int ty = tid >> 2;       // row within block (0..63)
    int r = row0 + ty;
    float a0 = bias[jg], a1 = bias[jg + 1], a2 = bias[jg + 2], a3 = bias[jg + 3];
#pragma unroll
    for (int k = 0; k < 64; ++k) {
        float hv = hs[ty][k], tv = ts[ty][k];
        float4 w0 = *(const float4*)&W0s[k * 16 + jg];
        float4 w1 = *(const float4*)&W1s[k * 16 + jg];
        a0 = fmaf(hv, w0.x, fmaf(tv, w1.x, a0));
        a1 = fmaf(hv, w0.y, fmaf(tv, w1.y, a1));
        a2 = fmaf(hv, w0.z, fmaf(tv, w1.z, a2));
        a3 = fmaf(hv, w0.w, fmaf(tv, w1.w, a3));
    }
    if (r < n) {
        float4 o = {a0, a1, a2, a3};
        *(float4*)&out[(size_t)r * 16 + jg] = o;
    }
}

// ---------------- launch ----------------

extern "C" void kernel_launch(void* const* d_in, const int* in_sizes, int n_in,
                              void* d_out, int out_size, void* d_ws, size_t ws_size,
                              hipStream_t stream) {
    const float* x    = (const float*)d_in[0];
    const int*   adj  = (const int*)d_in[1];
    const float* W1_0 = (const float*)d_in[2];
    const float* W1_1 = (const float*)d_in[3];
    const float* b1   = (const float*)d_in[4];
    const float* Wx_0 = (const float*)d_in[5];
    const float* Wx_1 = (const float*)d_in[6];
    const float* bx   = (const float*)d_in[7];
    const float* W2_0 = (const float*)d_in[8];
    const float* W2_1 = (const float*)d_in[9];
    const float* b2   = (const float*)d_in[10];
    float* out = (float*)d_out;

    int N = in_sizes[0] / 64;
    int E = in_sizes[1] / 2;
    const int* row = adj;
    const int* col = adj + E;
    int NBK = (N + 255) / 256;  // rows bucketed by row>>8; requires N <= 131072

    char* p = (char*)d_ws;
    auto alloc = [&](size_t bytes) {
        char* q = p;
        p += (bytes + 255) & ~(size_t)255;
        return q;
    };
    int*   bcnt  = (int*)alloc((size_t)(NBK) * 4);
    int*   bbase = (int*)alloc((size_t)(NBK + 1) * 4);
    int*   bcur  = (int*)alloc((size_t)(NBK) * 4);
    int*   off   = (int*)alloc((size_t)(N + 1) * 4);
    float* dis   = (float*)alloc((size_t)N * 4);
    int*   csr   = (int*)alloc((size_t)E * 4);
    float* y     = (float*)alloc((size_t)N * 64 * 4);
    float* tx    = (float*)alloc((size_t)N * 64 * 4);
    float* h     = (float*)alloc((size_t)N * 64 * 4);
    (void)ws_size;
    int* packed = (int*)tx;  // reuse: packed edges only live during CSR build

    int EB = (E + EPB - 1) / EPB;
    hipMemsetAsync(bcnt, 0, (size_t)NBK * 4, stream);
    bucket_count<<<EB, 256, 0, stream>>>(row, bcnt, E, NBK);
    bucket_scan<<<1, 256, 0, stream>>>(bcnt, bbase, bcur, off, NBK, N, E);
    bucket_scatter<<<EB, 256, 0, stream>>>(row, col, bcur, packed, E, NBK);
    bucket_build<<<NBK, 256, 0, stream>>>(packed, bbase, off, dis, csr, N);

    // layer 1
    scale_y<<<(N * 16 + 255) / 256, 256, 0, stream>>>(x, dis, y, N);
    aggregate<<<(N + 15) / 16, 256, 0, stream>>>(y, csr, off, dis, tx, N);
    dense64<true, true><<<(N + 31) / 32, 256, 0, stream>>>(x, tx, W1_0, W1_1, b1, dis, h, y, N);
    // layer x
    aggregate<<<(N + 15) / 16, 256, 0, stream>>>(y, csr, off, dis, tx, N);
    dense64<true, true><<<(N + 31) / 32, 256, 0, stream>>>(h, tx, Wx_0, Wx_1, bx, dis, h, y, N);
    // layer 2
    aggregate<<<(N + 15) / 16, 256, 0, stream>>>(y, csr, off, dis, tx, N);
    dense16<<<(N + 63) / 64, 256, 0, stream>>>(h, tx, W2_0, W2_1, b2, out, N);
}

// Round 5
// 369.422 us; speedup vs baseline: 3.5850x; 3.5850x over previous
//
#include <hip/hip_runtime.h>
#include <hip/hip_bf16.h>

// Two-level counting-sort CSR build:
//   bucket = row >> 8  (256 rows per bucket, NBK = ceil(N/256) <= 512 for N <= 131072)
//   packed edge record = (localrow << 17) | col   (needs N <= 2^17)

#define EPB 4096  // edges per block in bucket count/scatter

// ---- Pass A1: per-bucket edge counts ----
__global__ __launch_bounds__(256) void bucket_count(const int* __restrict__ row,
                                                    int* __restrict__ bcnt,
                                                    int e, int nbk) {
    __shared__ int bh[512];
    int tid = threadIdx.x;
    for (int j = tid; j < nbk; j += 256) bh[j] = 0;
    __syncthreads();
    int base = blockIdx.x * EPB;
#pragma unroll
    for (int k = 0; k < EPB / 256; ++k) {
        int i = base + k * 256 + tid;
        if (i < e) atomicAdd(&bh[row[i] >> 8], 1);
    }
    __syncthreads();
    for (int j = tid; j < nbk; j += 256) {
        int c = bh[j];
        if (c) atomicAdd(&bcnt[j], c);
    }
}

// ---- Pass A2: scan bucket counts (single block) ----
__global__ __launch_bounds__(256) void bucket_scan(const int* __restrict__ bcnt,
                                                   int* __restrict__ bbase,
                                                   int* __restrict__ bcursor,
                                                   int* __restrict__ off,
                                                   int nbk, int n, int e) {
    __shared__ int sa[512], sb[512];
    int tid = threadIdx.x;
    for (int j = tid; j < 512; j += 256) sa[j] = (j < nbk) ? bcnt[j] : 0;
    __syncthreads();
    int* in = sa;
    int* out = sb;
    for (int d = 1; d < 512; d <<= 1) {
        for (int j = tid; j < 512; j += 256)
            out[j] = in[j] + ((j >= d) ? in[j - d] : 0);
        __syncthreads();
        int* t = in; in = out; out = t;
    }
    for (int j = tid; j < nbk; j += 256) {
        int incl = in[j];
        int excl = incl - bcnt[j];
        bbase[j] = excl;
        bcursor[j] = excl;
        if (j == nbk - 1) bbase[nbk] = incl;
    }
    if (tid == 0) off[n] = e;
}

// ---- Pass A3: scatter packed edges into bucket regions ----
__global__ __launch_bounds__(256) void bucket_scatter(const int* __restrict__ row,
                                                      const int* __restrict__ col,
                                                      int* __restrict__ bcursor,
                                                      int* __restrict__ packed,
                                                      int e, int nbk) {
    __shared__ int bh[512];
    __shared__ int bbase[512];
    __shared__ int bcur[512];
    int tid = threadIdx.x;
    for (int j = tid; j < nbk; j += 256) { bh[j] = 0; bcur[j] = 0; }
    __syncthreads();
    int base = blockIdx.x * EPB;
#pragma unroll
    for (int k = 0; k < EPB / 256; ++k) {
        int i = base + k * 256 + tid;
        if (i < e) atomicAdd(&bh[row[i] >> 8], 1);
    }
    __syncthreads();
    for (int j = tid; j < nbk; j += 256) {
        int c = bh[j];
        bbase[j] = c ? atomicAdd(&bcursor[j], c) : 0;
    }
    __syncthreads();
#pragma unroll
    for (int k = 0; k < EPB / 256; ++k) {
        int i = base + k * 256 + tid;
        if (i < e) {
            int r = row[i];
            int b = r >> 8;
            int slot = bbase[b] + atomicAdd(&bcur[b], 1);
            packed[slot] = ((r & 255) << 17) | col[i];
        }
    }
}

// ---- Pass B: per-bucket row histogram + scan -> off/dis/csr ----
__global__ __launch_bounds__(256) void bucket_build(const int* __restrict__ packed,
                                                    const int* __restrict__ bbase,
                                                    int* __restrict__ off,
                                                    float* __restrict__ dis,
                                                    int* __restrict__ csr, int n) {
    __shared__ int rcnt[256];
    __shared__ int sa[256], sb[256];
    int tid = threadIdx.x;
    int b = blockIdx.x;
    int ebase = bbase[b], eend = bbase[b + 1];
    rcnt[tid] = 0;
    __syncthreads();
    for (int e = ebase + tid; e < eend; e += 256)
        atomicAdd(&rcnt[packed[e] >> 17], 1);
    __syncthreads();
    sa[tid] = rcnt[tid];
    __syncthreads();
    int* in = sa;
    int* out = sb;
    for (int d = 1; d < 256; d <<= 1) {
        out[tid] = in[tid] + ((tid >= d) ? in[tid - d] : 0);
        __syncthreads();
        int* t = in; in = out; out = t;
    }
    // in[tid] = inclusive scan; out is free for reuse as cursor
    int grow = b * 256 + tid;
    int c = rcnt[tid];
    int excl = in[tid] - c;
    if (grow < n) {
        off[grow] = ebase + excl;
        dis[grow] = (c > 0) ? rsqrtf((float)c) : 0.0f;
    }
    out[tid] = excl;
    __syncthreads();
    for (int e = ebase + tid; e < eend; e += 256) {
        int p = packed[e];
        int lr = p >> 17;
        int pos = atomicAdd(&out[lr], 1);
        csr[ebase + pos] = p & 0x1FFFF;
    }
}

// ---------------- y = dis[i] * x[i][:] ----------------

__global__ __launch_bounds__(256) void scale_y(const float* __restrict__ x,
                                               const float* __restrict__ dis,
                                               float* __restrict__ y, int n) {
    int id = blockIdx.x * 256 + threadIdx.x;  // over N*16 float4s
    if (id < n * 16) {
        int r = id >> 4;
        float d = dis[r];
        float4 v = ((const float4*)x)[id];
        float4 o = {v.x * d, v.y * d, v.z * d, v.w * d};
        ((float4*)y)[id] = o;
    }
}

// ---------------- aggregate: tx[r][f] = -dis[r] * sum_e y[col][f] ----------------
// thread = (row, feature-quad): 16 threads per row, 16 rows per block.

__global__ __launch_bounds__(256) void aggregate(const float* __restrict__ y,
                                                 const int* __restrict__ csr,
                                                 const int* __restrict__ off,
                                                 const float* __restrict__ dis,
                                                 float* __restrict__ tx, int n) {
    int tid = threadIdx.x;
    int r = blockIdx.x * 16 + (tid >> 4);
    if (r >= n) return;
    int q = tid & 15;
    int s0 = off[r], e1 = off[r + 1];
    const float4* Y = (const float4*)y;
    float ax = 0.f, ay = 0.f, az = 0.f, aw = 0.f;
    int t = s0;
    for (; t + 4 <= e1; t += 4) {
        int c0 = csr[t], c1 = csr[t + 1], c2 = csr[t + 2], c3 = csr[t + 3];
        float4 v0 = Y[(size_t)c0 * 16 + q];
        float4 v1 = Y[(size_t)c1 * 16 + q];
        float4 v2 = Y[(size_t)c2 * 16 + q];
        float4 v3 = Y[(size_t)c3 * 16 + q];
        ax += (v0.x + v1.x) + (v2.x + v3.x);
        ay += (v0.y + v1.y) + (v2.y + v3.y);
        az += (v0.z + v1.z) + (v2.z + v3.z);
        aw += (v0.w + v1.w) + (v2.w + v3.w);
    }
    for (; t < e1; ++t) {
        int c = csr[t];
        float4 v = Y[(size_t)c * 16 + q];
        ax += v.x; ay += v.y; az += v.z; aw += v.w;
    }
    float d = -dis[r];
    float4 o = {ax * d, ay * d, az * d, aw * d};
    *(float4*)&tx[(size_t)r * 64 + q * 4] = o;
}

// ---------------- dense: out = act(h@W0 + tx@W1 + b); optionally y = dis*out ----------------
// 1 row per thread, 16 rows per block. k-loop unroll capped at 8 to keep
// VGPR pressure low (full unroll at 2 rows/thread spilled: VGPR=256, 1.5 GB
// of scratch traffic per dispatch — round 2 post-mortem).

template <bool RELU, bool WRITE_Y>
__global__ __launch_bounds__(256) void dense64(const float* h_in,
                                               const float* __restrict__ tx,
                                               const float* __restrict__ W0,
                                               const float* __restrict__ W1,
                                               const float* __restrict__ bias,
                                               const float* __restrict__ dis,
                                               float* h_out,
                                               float* __restrict__ y, int n) {
    __shared__ float W0s[64 * 64];
    __shared__ float W1s[64 * 64];
    __shared__ float hs[16][68];
    __shared__ float ts[16][68];
    int tid = threadIdx.x;
    for (int idx = tid; idx < 4096; idx += 256) {
        W0s[idx] = W0[idx];
        W1s[idx] = W1[idx];
    }
    int row0 = blockIdx.x * 16;
    for (int idx = tid; idx < 1024; idx += 256) {
        int rr = idx >> 6, c = idx & 63;
        int r = row0 + rr;
        float hv = 0.f, tv = 0.f;
        if (r < n) {
            hv = h_in[(size_t)r * 64 + c];
            tv = tx[(size_t)r * 64 + c];
        }
        hs[rr][c] = hv;
        ts[rr][c] = tv;
    }
    __syncthreads();
    int jg = (tid & 15) * 4;  // column group
    int ty = tid >> 4;        // row within block (0..15)
    int r = row0 + ty;
    float a0 = bias[jg], a1 = bias[jg + 1], a2 = bias[jg + 2], a3 = bias[jg + 3];
#pragma unroll 8
    for (int k = 0; k < 64; ++k) {
        float hv = hs[ty][k], tv = ts[ty][k];
        float4 w0 = *(const float4*)&W0s[k * 64 + jg];
        float4 w1 = *(const float4*)&W1s[k * 64 + jg];
        a0 = fmaf(hv, w0.x, fmaf(tv, w1.x, a0));
        a1 = fmaf(hv, w0.y, fmaf(tv, w1.y, a1));
        a2 = fmaf(hv, w0.z, fmaf(tv, w1.z, a2));
        a3 = fmaf(hv, w0.w, fmaf(tv, w1.w, a3));
    }
    if (RELU) {
        a0 = fmaxf(a0, 0.f); a1 = fmaxf(a1, 0.f);
        a2 = fmaxf(a2, 0.f); a3 = fmaxf(a3, 0.f);
    }
    if (r < n) {
        float4 o = {a0, a1, a2, a3};
        *(float4*)&h_out[(size_t)r * 64 + jg] = o;
        if (WRITE_Y) {
            float dv = dis[r];
            float4 yv = {a0 * dv, a1 * dv, a2 * dv, a3 * dv};
            *(float4*)&y[(size_t)r * 64 + jg] = yv;
        }
    }
}

__global__ __launch_bounds__(256) void dense16(const float* __restrict__ h_in,
                                               const float* __restrict__ tx,
                                               const float* __restrict__ W0,
                                               const float* __restrict__ W1,
                                               const float* __restrict__ bias,
                                               float* __restrict__ out, int n) {
    __shared__ float W0s[64 * 16];
    __shared__ float W1s[64 * 16];
    __shared__ float hs[64][68];
    __shared__ float ts[64][68];
    int tid = threadIdx.x;
    for (int idx = tid; idx < 1024; idx += 256) {
        W0s[idx] = W0[idx];
        W1s[idx] = W1[idx];
    }
    int row0 = blockIdx.x * 64;
    for (int idx = tid; idx < 4096; idx += 256) {
        int rr = idx >> 6, c = idx & 63;
        int r = row0 + rr;
        float hv = 0.f, tv = 0.f;
        if (r < n) {
            hv = h_in[(size_t)r * 64 + c];
            tv = tx[(size_t)r * 64 + c];
        }
        hs[rr][c] = hv;
        ts[rr][c] = tv;
    }
    __syncthreads();
    int jg = (tid & 3) * 4;  // column group (16 cols -> 4 groups)
    int ty = tid >> 2;       // row within block (0..63)
    int r = row0 + ty;
    float a0 = bias[jg], a1 = bias[jg + 1], a2 = bias[jg + 2], a3 = bias[jg + 3];
#pragma unroll 8
    for (int k = 0; k < 64; ++k) {
        float hv = hs[ty][k], tv = ts[ty][k];
        float4 w0 = *(const float4*)&W0s[k * 16 + jg];
        float4 w1 = *(const float4*)&W1s[k * 16 + jg];
        a0 = fmaf(hv, w0.x, fmaf(tv, w1.x, a0));
        a1 = fmaf(hv, w0.y, fmaf(tv, w1.y, a1));
        a2 = fmaf(hv, w0.z, fmaf(tv, w1.z, a2));
        a3 = fmaf(hv, w0.w, fmaf(tv, w1.w, a3));
    }
    if (r < n) {
        float4 o = {a0, a1, a2, a3};
        *(float4*)&out[(size_t)r * 16 + jg] = o;
    }
}

// ---------------- launch ----------------

extern "C" void kernel_launch(void* const* d_in, const int* in_sizes, int n_in,
                              void* d_out, int out_size, void* d_ws, size_t ws_size,
                              hipStream_t stream) {
    const float* x    = (const float*)d_in[0];
    const int*   adj  = (const int*)d_in[1];
    const float* W1_0 = (const float*)d_in[2];
    const float* W1_1 = (const float*)d_in[3];
    const float* b1   = (const float*)d_in[4];
    const float* Wx_0 = (const float*)d_in[5];
    const float* Wx_1 = (const float*)d_in[6];
    const float* bx   = (const float*)d_in[7];
    const float* W2_0 = (const float*)d_in[8];
    const float* W2_1 = (const float*)d_in[9];
    const float* b2   = (const float*)d_in[10];
    float* out = (float*)d_out;

    int N = in_sizes[0] / 64;
    int E = in_sizes[1] / 2;
    const int* row = adj;
    const int* col = adj + E;
    int NBK = (N + 255) / 256;  // rows bucketed by row>>8; requires N <= 131072

    char* p = (char*)d_ws;
    auto alloc = [&](size_t bytes) {
        char* q = p;
        p += (bytes + 255) & ~(size_t)255;
        return q;
    };
    int*   bcnt  = (int*)alloc((size_t)(NBK) * 4);
    int*   bbase = (int*)alloc((size_t)(NBK + 1) * 4);
    int*   bcur  = (int*)alloc((size_t)(NBK) * 4);
    int*   off   = (int*)alloc((size_t)(N + 1) * 4);
    float* dis   = (float*)alloc((size_t)N * 4);
    int*   csr   = (int*)alloc((size_t)E * 4);
    float* y     = (float*)alloc((size_t)N * 64 * 4);
    float* tx    = (float*)alloc((size_t)N * 64 * 4);
    float* h     = (float*)alloc((size_t)N * 64 * 4);
    (void)ws_size;
    int* packed = (int*)tx;  // reuse: packed edges only live during CSR build

    int EB = (E + EPB - 1) / EPB;
    hipMemsetAsync(bcnt, 0, (size_t)NBK * 4, stream);
    bucket_count<<<EB, 256, 0, stream>>>(row, bcnt, E, NBK);
    bucket_scan<<<1, 256, 0, stream>>>(bcnt, bbase, bcur, off, NBK, N, E);
    bucket_scatter<<<EB, 256, 0, stream>>>(row, col, bcur, packed, E, NBK);
    bucket_build<<<NBK, 256, 0, stream>>>(packed, bbase, off, dis, csr, N);

    // layer 1
    scale_y<<<(N * 16 + 255) / 256, 256, 0, stream>>>(x, dis, y, N);
    aggregate<<<(N + 15) / 16, 256, 0, stream>>>(y, csr, off, dis, tx, N);
    dense64<true, true><<<(N + 15) / 16, 256, 0, stream>>>(x, tx, W1_0, W1_1, b1, dis, h, y, N);
    // layer x
    aggregate<<<(N + 15) / 16, 256, 0, stream>>>(y, csr, off, dis, tx, N);
    dense64<true, true><<<(N + 15) / 16, 256, 0, stream>>>(h, tx, Wx_0, Wx_1, bx, dis, h, y, N);
    // layer 2
    aggregate<<<(N + 15) / 16, 256, 0, stream>>>(y, csr, off, dis, tx, N);
    dense16<<<(N + 63) / 64, 256, 0, stream>>>(h, tx, W2_0, W2_1, b2, out, N);
}

// Round 6
// 303.215 us; speedup vs baseline: 4.3678x; 1.2184x over previous
//
#include <hip/hip_runtime.h>
#include <hip/hip_bf16.h>

// Two-level counting-sort CSR build:
//   bucket = row >> 8  (256 rows per bucket, NBK = ceil(N/256) <= 512 for N <= 131072)
//   packed edge record = (localrow << 17) | col   (needs N <= 2^17)

#define EPB 4096  // edges per block in bucket count/scatter

__device__ __forceinline__ float bf2f(unsigned short u) {
    unsigned int x = ((unsigned int)u) << 16;
    return __uint_as_float(x);
}
__device__ __forceinline__ unsigned short f2bf(float f) {
    unsigned int b = __float_as_uint(f);
    unsigned int r = (b + 0x7FFF + ((b >> 16) & 1)) >> 16;  // round-nearest-even
    return (unsigned short)r;
}

// ---- Pass A1: per-bucket edge counts ----
__global__ __launch_bounds__(256) void bucket_count(const int* __restrict__ row,
                                                    int* __restrict__ bcnt,
                                                    int e, int nbk) {
    __shared__ int bh[512];
    int tid = threadIdx.x;
    for (int j = tid; j < nbk; j += 256) bh[j] = 0;
    __syncthreads();
    int base = blockIdx.x * EPB;
#pragma unroll
    for (int k = 0; k < EPB / 256; ++k) {
        int i = base + k * 256 + tid;
        if (i < e) atomicAdd(&bh[row[i] >> 8], 1);
    }
    __syncthreads();
    for (int j = tid; j < nbk; j += 256) {
        int c = bh[j];
        if (c) atomicAdd(&bcnt[j], c);
    }
}

// ---- Pass A2: scan bucket counts (single block) ----
__global__ __launch_bounds__(256) void bucket_scan(const int* __restrict__ bcnt,
                                                   int* __restrict__ bbase,
                                                   int* __restrict__ bcursor,
                                                   int* __restrict__ off,
                                                   int nbk, int n, int e) {
    __shared__ int sa[512], sb[512];
    int tid = threadIdx.x;
    for (int j = tid; j < 512; j += 256) sa[j] = (j < nbk) ? bcnt[j] : 0;
    __syncthreads();
    int* in = sa;
    int* out = sb;
    for (int d = 1; d < 512; d <<= 1) {
        for (int j = tid; j < 512; j += 256)
            out[j] = in[j] + ((j >= d) ? in[j - d] : 0);
        __syncthreads();
        int* t = in; in = out; out = t;
    }
    for (int j = tid; j < nbk; j += 256) {
        int incl = in[j];
        int excl = incl - bcnt[j];
        bbase[j] = excl;
        bcursor[j] = excl;
        if (j == nbk - 1) bbase[nbk] = incl;
    }
    if (tid == 0) off[n] = e;
}

// ---- Pass A3: scatter packed edges into bucket regions ----
__global__ __launch_bounds__(256) void bucket_scatter(const int* __restrict__ row,
                                                      const int* __restrict__ col,
                                                      int* __restrict__ bcursor,
                                                      int* __restrict__ packed,
                                                      int e, int nbk) {
    __shared__ int bh[512];
    __shared__ int bbase[512];
    __shared__ int bcur[512];
    int tid = threadIdx.x;
    for (int j = tid; j < nbk; j += 256) { bh[j] = 0; bcur[j] = 0; }
    __syncthreads();
    int base = blockIdx.x * EPB;
#pragma unroll
    for (int k = 0; k < EPB / 256; ++k) {
        int i = base + k * 256 + tid;
        if (i < e) atomicAdd(&bh[row[i] >> 8], 1);
    }
    __syncthreads();
    for (int j = tid; j < nbk; j += 256) {
        int c = bh[j];
        bbase[j] = c ? atomicAdd(&bcursor[j], c) : 0;
    }
    __syncthreads();
#pragma unroll
    for (int k = 0; k < EPB / 256; ++k) {
        int i = base + k * 256 + tid;
        if (i < e) {
            int r = row[i];
            int b = r >> 8;
            int slot = bbase[b] + atomicAdd(&bcur[b], 1);
            packed[slot] = ((r & 255) << 17) | col[i];
        }
    }
}

// ---- Pass B: per-bucket row histogram + scan -> off/dis/csr ----
__global__ __launch_bounds__(256) void bucket_build(const int* __restrict__ packed,
                                                    const int* __restrict__ bbase,
                                                    int* __restrict__ off,
                                                    float* __restrict__ dis,
                                                    int* __restrict__ csr, int n) {
    __shared__ int rcnt[256];
    __shared__ int sa[256], sb[256];
    int tid = threadIdx.x;
    int b = blockIdx.x;
    int ebase = bbase[b], eend = bbase[b + 1];
    rcnt[tid] = 0;
    __syncthreads();
    for (int e = ebase + tid; e < eend; e += 256)
        atomicAdd(&rcnt[packed[e] >> 17], 1);
    __syncthreads();
    sa[tid] = rcnt[tid];
    __syncthreads();
    int* in = sa;
    int* out = sb;
    for (int d = 1; d < 256; d <<= 1) {
        out[tid] = in[tid] + ((tid >= d) ? in[tid - d] : 0);
        __syncthreads();
        int* t = in; in = out; out = t;
    }
    // in[tid] = inclusive scan; out is free for reuse as cursor
    int grow = b * 256 + tid;
    int c = rcnt[tid];
    int excl = in[tid] - c;
    if (grow < n) {
        off[grow] = ebase + excl;
        dis[grow] = (c > 0) ? rsqrtf((float)c) : 0.0f;
    }
    out[tid] = excl;
    __syncthreads();
    for (int e = ebase + tid; e < eend; e += 256) {
        int p = packed[e];
        int lr = p >> 17;
        int pos = atomicAdd(&out[lr], 1);
        csr[ebase + pos] = p & 0x1FFFF;
    }
}

// ---------------- y[i][:] = bf16(dis[i] * x[i][:]) ----------------

__global__ __launch_bounds__(256) void scale_y(const float* __restrict__ x,
                                               const float* __restrict__ dis,
                                               unsigned short* __restrict__ y, int n) {
    int id = blockIdx.x * 256 + threadIdx.x;  // over N*16 quads
    if (id < n * 16) {
        int r = id >> 4;
        float d = dis[r];
        float4 v = ((const float4*)x)[id];
        ushort4 o = {f2bf(v.x * d), f2bf(v.y * d), f2bf(v.z * d), f2bf(v.w * d)};
        ((ushort4*)y)[id] = o;
    }
}

// ---------------- aggregate: tx[r][f] = -dis[r] * sum_e y[col][f] ----------------
// thread = (row, feature-quad): 16 threads per row, 16 rows per block.
// y is bf16: 8 B gathered per lane per edge (128 B per row) — half the fp32 traffic.

__global__ __launch_bounds__(256) void aggregate(const unsigned short* __restrict__ y,
                                                 const int* __restrict__ csr,
                                                 const int* __restrict__ off,
                                                 const float* __restrict__ dis,
                                                 float* __restrict__ tx, int n) {
    int tid = threadIdx.x;
    int r = blockIdx.x * 16 + (tid >> 4);
    if (r >= n) return;
    int q = tid & 15;
    int s0 = off[r], e1 = off[r + 1];
    const ushort4* Y = (const ushort4*)y;
    float ax = 0.f, ay = 0.f, az = 0.f, aw = 0.f;
    int t = s0;
    for (; t + 4 <= e1; t += 4) {
        int c0 = csr[t], c1 = csr[t + 1], c2 = csr[t + 2], c3 = csr[t + 3];
        ushort4 v0 = Y[(size_t)c0 * 16 + q];
        ushort4 v1 = Y[(size_t)c1 * 16 + q];
        ushort4 v2 = Y[(size_t)c2 * 16 + q];
        ushort4 v3 = Y[(size_t)c3 * 16 + q];
        ax += (bf2f(v0.x) + bf2f(v1.x)) + (bf2f(v2.x) + bf2f(v3.x));
        ay += (bf2f(v0.y) + bf2f(v1.y)) + (bf2f(v2.y) + bf2f(v3.y));
        az += (bf2f(v0.z) + bf2f(v1.z)) + (bf2f(v2.z) + bf2f(v3.z));
        aw += (bf2f(v0.w) + bf2f(v1.w)) + (bf2f(v2.w) + bf2f(v3.w));
    }
    for (; t < e1; ++t) {
        int c = csr[t];
        ushort4 v = Y[(size_t)c * 16 + q];
        ax += bf2f(v.x); ay += bf2f(v.y); az += bf2f(v.z); aw += bf2f(v.w);
    }
    float d = -dis[r];
    float4 o = {ax * d, ay * d, az * d, aw * d};
    *(float4*)&tx[(size_t)r * 64 + q * 4] = o;
}

// ---------------- dense: out = act(h@W0 + tx@W1 + b); optionally y = bf16(dis*out) ----------------
// 1 row per thread, 16 rows per block. k-loop unroll capped at 8 to keep
// VGPR pressure low (full unroll at 2 rows/thread spilled: VGPR=256, 1.5 GB
// of scratch traffic per dispatch — round 2 post-mortem).

template <bool RELU, bool WRITE_Y>
__global__ __launch_bounds__(256) void dense64(const float* h_in,
                                               const float* __restrict__ tx,
                                               const float* __restrict__ W0,
                                               const float* __restrict__ W1,
                                               const float* __restrict__ bias,
                                               const float* __restrict__ dis,
                                               float* h_out,
                                               unsigned short* __restrict__ y, int n) {
    __shared__ float W0s[64 * 64];
    __shared__ float W1s[64 * 64];
    __shared__ float hs[16][68];
    __shared__ float ts[16][68];
    int tid = threadIdx.x;
    for (int idx = tid; idx < 4096; idx += 256) {
        W0s[idx] = W0[idx];
        W1s[idx] = W1[idx];
    }
    int row0 = blockIdx.x * 16;
    for (int idx = tid; idx < 1024; idx += 256) {
        int rr = idx >> 6, c = idx & 63;
        int r = row0 + rr;
        float hv = 0.f, tv = 0.f;
        if (r < n) {
            hv = h_in[(size_t)r * 64 + c];
            tv = tx[(size_t)r * 64 + c];
        }
        hs[rr][c] = hv;
        ts[rr][c] = tv;
    }
    __syncthreads();
    int jg = (tid & 15) * 4;  // column group
    int ty = tid >> 4;        // row within block (0..15)
    int r = row0 + ty;
    float a0 = bias[jg], a1 = bias[jg + 1], a2 = bias[jg + 2], a3 = bias[jg + 3];
#pragma unroll 8
    for (int k = 0; k < 64; ++k) {
        float hv = hs[ty][k], tv = ts[ty][k];
        float4 w0 = *(const float4*)&W0s[k * 64 + jg];
        float4 w1 = *(const float4*)&W1s[k * 64 + jg];
        a0 = fmaf(hv, w0.x, fmaf(tv, w1.x, a0));
        a1 = fmaf(hv, w0.y, fmaf(tv, w1.y, a1));
        a2 = fmaf(hv, w0.z, fmaf(tv, w1.z, a2));
        a3 = fmaf(hv, w0.w, fmaf(tv, w1.w, a3));
    }
    if (RELU) {
        a0 = fmaxf(a0, 0.f); a1 = fmaxf(a1, 0.f);
        a2 = fmaxf(a2, 0.f); a3 = fmaxf(a3, 0.f);
    }
    if (r < n) {
        float4 o = {a0, a1, a2, a3};
        *(float4*)&h_out[(size_t)r * 64 + jg] = o;
        if (WRITE_Y) {
            float dv = dis[r];
            ushort4 yv = {f2bf(a0 * dv), f2bf(a1 * dv), f2bf(a2 * dv), f2bf(a3 * dv)};
            *(ushort4*)&y[(size_t)r * 64 + jg] = yv;
        }
    }
}

__global__ __launch_bounds__(256) void dense16(const float* __restrict__ h_in,
                                               const float* __restrict__ tx,
                                               const float* __restrict__ W0,
                                               const float* __restrict__ W1,
                                               const float* __restrict__ bias,
                                               float* __restrict__ out, int n) {
    __shared__ float W0s[64 * 16];
    __shared__ float W1s[64 * 16];
    __shared__ float hs[64][68];
    __shared__ float ts[64][68];
    int tid = threadIdx.x;
    for (int idx = tid; idx < 1024; idx += 256) {
        W0s[idx] = W0[idx];
        W1s[idx] = W1[idx];
    }
    int row0 = blockIdx.x * 64;
    for (int idx = tid; idx < 4096; idx += 256) {
        int rr = idx >> 6, c = idx & 63;
        int r = row0 + rr;
        float hv = 0.f, tv = 0.f;
        if (r < n) {
            hv = h_in[(size_t)r * 64 + c];
            tv = tx[(size_t)r * 64 + c];
        }
        hs[rr][c] = hv;
        ts[rr][c] = tv;
    }
    __syncthreads();
    int jg = (tid & 3) * 4;  // column group (16 cols -> 4 groups)
    int ty = tid >> 2;       // row within block (0..63)
    int r = row0 + ty;
    float a0 = bias[jg], a1 = bias[jg + 1], a2 = bias[jg + 2], a3 = bias[jg + 3];
#pragma unroll 8
    for (int k = 0; k < 64; ++k) {
        float hv = hs[ty][k], tv = ts[ty][k];
        float4 w0 = *(const float4*)&W0s[k * 16 + jg];
        float4 w1 = *(const float4*)&W1s[k * 16 + jg];
        a0 = fmaf(hv, w0.x, fmaf(tv, w1.x, a0));
        a1 = fmaf(hv, w0.y, fmaf(tv, w1.y, a1));
        a2 = fmaf(hv, w0.z, fmaf(tv, w1.z, a2));
        a3 = fmaf(hv, w0.w, fmaf(tv, w1.w, a3));
    }
    if (r < n) {
        float4 o = {a0, a1, a2, a3};
        *(float4*)&out[(size_t)r * 16 + jg] = o;
    }
}

// ---------------- launch ----------------

extern "C" void kernel_launch(void* const* d_in, const int* in_sizes, int n_in,
                              void* d_out, int out_size, void* d_ws, size_t ws_size,
                              hipStream_t stream) {
    const float* x    = (const float*)d_in[0];
    const int*   adj  = (const int*)d_in[1];
    const float* W1_0 = (const float*)d_in[2];
    const float* W1_1 = (const float*)d_in[3];
    const float* b1   = (const float*)d_in[4];
    const float* Wx_0 = (const float*)d_in[5];
    const float* Wx_1 = (const float*)d_in[6];
    const float* bx   = (const float*)d_in[7];
    const float* W2_0 = (const float*)d_in[8];
    const float* W2_1 = (const float*)d_in[9];
    const float* b2   = (const float*)d_in[10];
    float* out = (float*)d_out;

    int N = in_sizes[0] / 64;
    int E = in_sizes[1] / 2;
    const int* row = adj;
    const int* col = adj + E;
    int NBK = (N + 255) / 256;  // rows bucketed by row>>8; requires N <= 131072

    char* p = (char*)d_ws;
    auto alloc = [&](size_t bytes) {
        char* q = p;
        p += (bytes + 255) & ~(size_t)255;
        return q;
    };
    int*   bcnt  = (int*)alloc((size_t)(NBK) * 4);
    int*   bbase = (int*)alloc((size_t)(NBK + 1) * 4);
    int*   bcur  = (int*)alloc((size_t)(NBK) * 4);
    int*   off   = (int*)alloc((size_t)(N + 1) * 4);
    float* dis   = (float*)alloc((size_t)N * 4);
    int*   csr   = (int*)alloc((size_t)E * 4);
    unsigned short* y = (unsigned short*)alloc((size_t)N * 64 * 2);
    float* tx    = (float*)alloc((size_t)N * 64 * 4);
    float* h     = (float*)alloc((size_t)N * 64 * 4);
    (void)ws_size;
    int* packed = (int*)tx;  // reuse: packed edges only live during CSR build

    int EB = (E + EPB - 1) / EPB;
    hipMemsetAsync(bcnt, 0, (size_t)NBK * 4, stream);
    bucket_count<<<EB, 256, 0, stream>>>(row, bcnt, E, NBK);
    bucket_scan<<<1, 256, 0, stream>>>(bcnt, bbase, bcur, off, NBK, N, E);
    bucket_scatter<<<EB, 256, 0, stream>>>(row, col, bcur, packed, E, NBK);
    bucket_build<<<NBK, 256, 0, stream>>>(packed, bbase, off, dis, csr, N);

    // layer 1
    scale_y<<<(N * 16 + 255) / 256, 256, 0, stream>>>(x, dis, y, N);
    aggregate<<<(N + 15) / 16, 256, 0, stream>>>(y, csr, off, dis, tx, N);
    dense64<true, true><<<(N + 15) / 16, 256, 0, stream>>>(x, tx, W1_0, W1_1, b1, dis, h, y, N);
    // layer x
    aggregate<<<(N + 15) / 16, 256, 0, stream>>>(y, csr, off, dis, tx, N);
    dense64<true, true><<<(N + 15) / 16, 256, 0, stream>>>(h, tx, Wx_0, Wx_1, bx, dis, h, y, N);
    // layer 2
    aggregate<<<(N + 15) / 16, 256, 0, stream>>>(y, csr, off, dis, tx, N);
    dense16<<<(N + 63) / 64, 256, 0, stream>>>(h, tx, W2_0, W2_1, b2, out, N);
}

// Round 7
// 214.092 us; speedup vs baseline: 6.1860x; 1.4163x over previous
//
#include <hip/hip_runtime.h>
#include <hip/hip_bf16.h>

// Two-level counting-sort CSR build:
//   bucket = row >> 8  (256 rows per bucket, NBK = ceil(N/256) <= 512 for N <= 131072)
//   packed edge record = (localrow << 17) | col   (needs N <= 2^17)

#define EPB 4096  // edges per block in bucket count/scatter

typedef __attribute__((ext_vector_type(8))) short bf16x8;
typedef __attribute__((ext_vector_type(4))) float f32x4;

__device__ __forceinline__ float bf2f(unsigned short u) {
    unsigned int x = ((unsigned int)u) << 16;
    return __uint_as_float(x);
}
__device__ __forceinline__ unsigned short f2bf(float f) {
    unsigned int b = __float_as_uint(f);
    unsigned int r = (b + 0x7FFF + ((b >> 16) & 1)) >> 16;  // round-nearest-even
    return (unsigned short)r;
}

// ---- Pass A1: per-bucket edge counts ----
__global__ __launch_bounds__(256) void bucket_count(const int* __restrict__ row,
                                                    int* __restrict__ bcnt,
                                                    int e, int nbk) {
    __shared__ int bh[512];
    int tid = threadIdx.x;
    for (int j = tid; j < nbk; j += 256) bh[j] = 0;
    __syncthreads();
    int base = blockIdx.x * EPB;
#pragma unroll
    for (int k = 0; k < EPB / 256; ++k) {
        int i = base + k * 256 + tid;
        if (i < e) atomicAdd(&bh[row[i] >> 8], 1);
    }
    __syncthreads();
    for (int j = tid; j < nbk; j += 256) {
        int c = bh[j];
        if (c) atomicAdd(&bcnt[j], c);
    }
}

// ---- Pass A2: scan bucket counts (single block) ----
__global__ __launch_bounds__(256) void bucket_scan(const int* __restrict__ bcnt,
                                                   int* __restrict__ bbase,
                                                   int* __restrict__ bcursor,
                                                   int* __restrict__ off,
                                                   int nbk, int n, int e) {
    __shared__ int sa[512], sb[512];
    int tid = threadIdx.x;
    for (int j = tid; j < 512; j += 256) sa[j] = (j < nbk) ? bcnt[j] : 0;
    __syncthreads();
    int* in = sa;
    int* out = sb;
    for (int d = 1; d < 512; d <<= 1) {
        for (int j = tid; j < 512; j += 256)
            out[j] = in[j] + ((j >= d) ? in[j - d] : 0);
        __syncthreads();
        int* t = in; in = out; out = t;
    }
    for (int j = tid; j < nbk; j += 256) {
        int incl = in[j];
        int excl = incl - bcnt[j];
        bbase[j] = excl;
        bcursor[j] = excl;
        if (j == nbk - 1) bbase[nbk] = incl;
    }
    if (tid == 0) off[n] = e;
}

// ---- Pass A3: scatter packed edges into bucket regions ----
__global__ __launch_bounds__(256) void bucket_scatter(const int* __restrict__ row,
                                                      const int* __restrict__ col,
                                                      int* __restrict__ bcursor,
                                                      int* __restrict__ packed,
                                                      int e, int nbk) {
    __shared__ int bh[512];
    __shared__ int bbase[512];
    __shared__ int bcur[512];
    int tid = threadIdx.x;
    for (int j = tid; j < nbk; j += 256) { bh[j] = 0; bcur[j] = 0; }
    __syncthreads();
    int base = blockIdx.x * EPB;
#pragma unroll
    for (int k = 0; k < EPB / 256; ++k) {
        int i = base + k * 256 + tid;
        if (i < e) atomicAdd(&bh[row[i] >> 8], 1);
    }
    __syncthreads();
    for (int j = tid; j < nbk; j += 256) {
        int c = bh[j];
        bbase[j] = c ? atomicAdd(&bcursor[j], c) : 0;
    }
    __syncthreads();
#pragma unroll
    for (int k = 0; k < EPB / 256; ++k) {
        int i = base + k * 256 + tid;
        if (i < e) {
            int r = row[i];
            int b = r >> 8;
            int slot = bbase[b] + atomicAdd(&bcur[b], 1);
            packed[slot] = ((r & 255) << 17) | col[i];
        }
    }
}

// ---- Pass B: per-bucket row histogram + scan -> off/dis/csr ----
__global__ __launch_bounds__(256) void bucket_build(const int* __restrict__ packed,
                                                    const int* __restrict__ bbase,
                                                    int* __restrict__ off,
                                                    float* __restrict__ dis,
                                                    int* __restrict__ csr, int n) {
    __shared__ int rcnt[256];
    __shared__ int sa[256], sb[256];
    int tid = threadIdx.x;
    int b = blockIdx.x;
    int ebase = bbase[b], eend = bbase[b + 1];
    rcnt[tid] = 0;
    __syncthreads();
    for (int e = ebase + tid; e < eend; e += 256)
        atomicAdd(&rcnt[packed[e] >> 17], 1);
    __syncthreads();
    sa[tid] = rcnt[tid];
    __syncthreads();
    int* in = sa;
    int* out = sb;
    for (int d = 1; d < 256; d <<= 1) {
        out[tid] = in[tid] + ((tid >= d) ? in[tid - d] : 0);
        __syncthreads();
        int* t = in; in = out; out = t;
    }
    // in[tid] = inclusive scan; out is free for reuse as cursor
    int grow = b * 256 + tid;
    int c = rcnt[tid];
    int excl = in[tid] - c;
    if (grow < n) {
        off[grow] = ebase + excl;
        dis[grow] = (c > 0) ? rsqrtf((float)c) : 0.0f;
    }
    out[tid] = excl;
    __syncthreads();
    for (int e = ebase + tid; e < eend; e += 256) {
        int p = packed[e];
        int lr = p >> 17;
        int pos = atomicAdd(&out[lr], 1);
        csr[ebase + pos] = p & 0x1FFFF;
    }
}

// ---------------- y = bf16(dis*x), xb = bf16(x) ----------------

__global__ __launch_bounds__(256) void scale_xy(const float* __restrict__ x,
                                                const float* __restrict__ dis,
                                                unsigned short* __restrict__ y,
                                                unsigned short* __restrict__ xb, int n) {
    int id = blockIdx.x * 256 + threadIdx.x;  // over N*16 quads
    if (id < n * 16) {
        int r = id >> 4;
        float d = dis[r];
        float4 v = ((const float4*)x)[id];
        ushort4 o = {f2bf(v.x * d), f2bf(v.y * d), f2bf(v.z * d), f2bf(v.w * d)};
        ((ushort4*)y)[id] = o;
        ushort4 xo = {f2bf(v.x), f2bf(v.y), f2bf(v.z), f2bf(v.w)};
        ((ushort4*)xb)[id] = xo;
    }
}

// ---------------- aggregate: tx[r][f] = bf16(-dis[r] * sum_e y[col][f]) ----------------
// thread = (row, feature-quad): 16 threads per row, 16 rows per block.
// y is bf16: 8 B gathered per lane per edge; fp32 accumulate; tx stored bf16.

__global__ __launch_bounds__(256) void aggregate(const unsigned short* __restrict__ y,
                                                 const int* __restrict__ csr,
                                                 const int* __restrict__ off,
                                                 const float* __restrict__ dis,
                                                 unsigned short* __restrict__ tx, int n) {
    int tid = threadIdx.x;
    int r = blockIdx.x * 16 + (tid >> 4);
    if (r >= n) return;
    int q = tid & 15;
    int s0 = off[r], e1 = off[r + 1];
    const ushort4* Y = (const ushort4*)y;
    float ax = 0.f, ay = 0.f, az = 0.f, aw = 0.f;
    int t = s0;
    for (; t + 4 <= e1; t += 4) {
        int c0 = csr[t], c1 = csr[t + 1], c2 = csr[t + 2], c3 = csr[t + 3];
        ushort4 v0 = Y[(size_t)c0 * 16 + q];
        ushort4 v1 = Y[(size_t)c1 * 16 + q];
        ushort4 v2 = Y[(size_t)c2 * 16 + q];
        ushort4 v3 = Y[(size_t)c3 * 16 + q];
        ax += (bf2f(v0.x) + bf2f(v1.x)) + (bf2f(v2.x) + bf2f(v3.x));
        ay += (bf2f(v0.y) + bf2f(v1.y)) + (bf2f(v2.y) + bf2f(v3.y));
        az += (bf2f(v0.z) + bf2f(v1.z)) + (bf2f(v2.z) + bf2f(v3.z));
        aw += (bf2f(v0.w) + bf2f(v1.w)) + (bf2f(v2.w) + bf2f(v3.w));
    }
    for (; t < e1; ++t) {
        int c = csr[t];
        ushort4 v = Y[(size_t)c * 16 + q];
        ax += bf2f(v.x); ay += bf2f(v.y); az += bf2f(v.z); aw += bf2f(v.w);
    }
    float d = -dis[r];
    ushort4 o = {f2bf(ax * d), f2bf(ay * d), f2bf(az * d), f2bf(aw * d)};
    *(ushort4*)&tx[(size_t)r * 64 + q * 4] = o;
}

// ---------------- dense via MFMA ----------------
// out[N x NC] = act( [A0 | A1] (N x 128, bf16) @ [W0; W1] (128 x NC, fp32->bf16) + b )
// mfma_f32_16x16x32_bf16, one 16-row x NC tile per wave, grid-stride over row blocks.
// B-fragments (the whole weight matrix) live in registers: NT*4 frags = NT*16 VGPRs,
// loaded once per thread and amortized over the row loop. No LDS, no barriers.
// k-slot labeling k = kt*32 + g*8 + i is used identically for A and B loads, so the
// result is invariant to the hardware's internal per-lane k order (bijection cancels).
// Load-bearing layout facts: A row = lane&15, B col = lane&15, k-group = lane>>4;
// D: col = lane&15, row = 4*(lane>>4)+reg  [verified m89/m91].

template <int NC, bool RELU, bool WRITE_HY>
__global__ __launch_bounds__(256) void dense_mfma(const unsigned short* __restrict__ A0,
                                                  const unsigned short* __restrict__ A1,
                                                  const float* __restrict__ W0,
                                                  const float* __restrict__ W1,
                                                  const float* __restrict__ bias,
                                                  const float* __restrict__ dis,
                                                  unsigned short* __restrict__ hout,
                                                  unsigned short* __restrict__ yout,
                                                  float* __restrict__ fout,
                                                  int n, int nrb) {
    constexpr int NT = NC / 16;
    int lane = threadIdx.x & 63;
    int m = lane & 15;   // A row / B col / D col within tile
    int g = lane >> 4;   // k-group
    bf16x8 bf[NT][4];
#pragma unroll
    for (int kt = 0; kt < 4; ++kt) {
        const float* W = (kt < 2) ? W0 : W1;
        int kb = (kt & 1) * 32 + g * 8;
#pragma unroll
        for (int nt = 0; nt < NT; ++nt) {
#pragma unroll
            for (int i = 0; i < 8; ++i)
                bf[nt][kt][i] = (short)f2bf(W[(kb + i) * NC + nt * 16 + m]);
        }
    }
    int wrb = blockIdx.x * 4 + (threadIdx.x >> 6);
    int stride = gridDim.x * 4;
    for (int rb = wrb; rb < nrb; rb += stride) {
        int r0 = rb * 16;
        int ra = r0 + m;
        if (ra > n - 1) ra = n - 1;  // clamped read; write is masked below
        const unsigned short* q0 = A0 + (size_t)ra * 64 + g * 8;
        const unsigned short* q1 = A1 + (size_t)ra * 64 + g * 8;
        bf16x8 a0 = *(const bf16x8*)q0;
        bf16x8 a1 = *(const bf16x8*)(q0 + 32);
        bf16x8 a2 = *(const bf16x8*)q1;
        bf16x8 a3 = *(const bf16x8*)(q1 + 32);
        f32x4 acc[NT];
#pragma unroll
        for (int nt = 0; nt < NT; ++nt) {
            float b = bias[nt * 16 + m];
            acc[nt][0] = b; acc[nt][1] = b; acc[nt][2] = b; acc[nt][3] = b;
        }
#pragma unroll
        for (int nt = 0; nt < NT; ++nt) {
            acc[nt] = __builtin_amdgcn_mfma_f32_16x16x32_bf16(a0, bf[nt][0], acc[nt], 0, 0, 0);
            acc[nt] = __builtin_amdgcn_mfma_f32_16x16x32_bf16(a1, bf[nt][1], acc[nt], 0, 0, 0);
            acc[nt] = __builtin_amdgcn_mfma_f32_16x16x32_bf16(a2, bf[nt][2], acc[nt], 0, 0, 0);
            acc[nt] = __builtin_amdgcn_mfma_f32_16x16x32_bf16(a3, bf[nt][3], acc[nt], 0, 0, 0);
        }
#pragma unroll
        for (int reg = 0; reg < 4; ++reg) {
            int rr = r0 + 4 * g + reg;
            if (rr >= n) continue;
            if (WRITE_HY) {
                float dv = dis[rr];
#pragma unroll
                for (int nt = 0; nt < NT; ++nt) {
                    float v = acc[nt][reg];
                    if (RELU) v = fmaxf(v, 0.f);
                    hout[(size_t)rr * NC + nt * 16 + m] = f2bf(v);
                    yout[(size_t)rr * NC + nt * 16 + m] = f2bf(v * dv);
                }
            } else {
#pragma unroll
                for (int nt = 0; nt < NT; ++nt)
                    fout[(size_t)rr * NC + nt * 16 + m] = acc[nt][reg];
            }
        }
    }
}

// ---------------- launch ----------------

extern "C" void kernel_launch(void* const* d_in, const int* in_sizes, int n_in,
                              void* d_out, int out_size, void* d_ws, size_t ws_size,
                              hipStream_t stream) {
    const float* x    = (const float*)d_in[0];
    const int*   adj  = (const int*)d_in[1];
    const float* W1_0 = (const float*)d_in[2];
    const float* W1_1 = (const float*)d_in[3];
    const float* b1   = (const float*)d_in[4];
    const float* Wx_0 = (const float*)d_in[5];
    const float* Wx_1 = (const float*)d_in[6];
    const float* bx   = (const float*)d_in[7];
    const float* W2_0 = (const float*)d_in[8];
    const float* W2_1 = (const float*)d_in[9];
    const float* b2   = (const float*)d_in[10];
    float* out = (float*)d_out;

    int N = in_sizes[0] / 64;
    int E = in_sizes[1] / 2;
    const int* row = adj;
    const int* col = adj + E;
    int NBK = (N + 255) / 256;  // rows bucketed by row>>8; requires N <= 131072
    int nRB = (N + 15) / 16;

    char* p = (char*)d_ws;
    auto alloc = [&](size_t bytes) {
        char* q = p;
        p += (bytes + 255) & ~(size_t)255;
        return q;
    };
    int*   bcnt  = (int*)alloc((size_t)(NBK) * 4);
    int*   bbase = (int*)alloc((size_t)(NBK + 1) * 4);
    int*   bcur  = (int*)alloc((size_t)(NBK) * 4);
    int*   off   = (int*)alloc((size_t)(N + 1) * 4);
    float* dis   = (float*)alloc((size_t)N * 4);
    int*   csr   = (int*)alloc((size_t)E * 4);
    unsigned short* y  = (unsigned short*)alloc((size_t)N * 64 * 2);
    unsigned short* xb = (unsigned short*)alloc((size_t)N * 64 * 2);
    unsigned short* tx = (unsigned short*)alloc((size_t)N * 64 * 2);
    unsigned short* h  = (unsigned short*)alloc((size_t)N * 64 * 2);
    (void)ws_size;
    int* packed = (int*)tx;  // reuse: packed edges (E*4 B) only live during CSR build

    int EB = (E + EPB - 1) / EPB;
    hipMemsetAsync(bcnt, 0, (size_t)NBK * 4, stream);
    bucket_count<<<EB, 256, 0, stream>>>(row, bcnt, E, NBK);
    bucket_scan<<<1, 256, 0, stream>>>(bcnt, bbase, bcur, off, NBK, N, E);
    bucket_scatter<<<EB, 256, 0, stream>>>(row, col, bcur, packed, E, NBK);
    bucket_build<<<NBK, 256, 0, stream>>>(packed, bbase, off, dis, csr, N);

    const int DG = 512;  // dense grid: 2048 waves, ~3 row-block iters each
    // layer 1
    scale_xy<<<(N * 16 + 255) / 256, 256, 0, stream>>>(x, dis, y, xb, N);
    aggregate<<<(N + 15) / 16, 256, 0, stream>>>(y, csr, off, dis, tx, N);
    dense_mfma<64, true, true><<<DG, 256, 0, stream>>>(xb, tx, W1_0, W1_1, b1, dis, h, y, nullptr, N, nRB);
    // layer x
    aggregate<<<(N + 15) / 16, 256, 0, stream>>>(y, csr, off, dis, tx, N);
    dense_mfma<64, true, true><<<DG, 256, 0, stream>>>(h, tx, Wx_0, Wx_1, bx, dis, h, y, nullptr, N, nRB);
    // layer 2
    aggregate<<<(N + 15) / 16, 256, 0, stream>>>(y, csr, off, dis, tx, N);
    dense_mfma<16, false, false><<<DG, 256, 0, stream>>>(h, tx, W2_0, W2_1, b2, dis, nullptr, nullptr, out, N, nRB);
}

// Round 8
// 203.502 us; speedup vs baseline: 6.5079x; 1.0520x over previous
//
#include <hip/hip_runtime.h>
#include <hip/hip_bf16.h>

// Two-level counting-sort CSR build:
//   bucket = row >> 8  (256 rows per bucket, NBK = ceil(N/256) <= 512 for N <= 131072)
//   packed edge record = (localrow << 17) | col   (needs N <= 2^17)

#define EPB 4096  // edges per block in bucket count/scatter

typedef __attribute__((ext_vector_type(8))) short bf16x8;
typedef __attribute__((ext_vector_type(4))) float f32x4;

__device__ __forceinline__ float bf2f(unsigned short u) {
    unsigned int x = ((unsigned int)u) << 16;
    return __uint_as_float(x);
}
__device__ __forceinline__ unsigned short f2bf(float f) {
    unsigned int b = __float_as_uint(f);
    unsigned int r = (b + 0x7FFF + ((b >> 16) & 1)) >> 16;  // round-nearest-even
    return (unsigned short)r;
}

// ---- tiny zero kernel (hipMemsetAsync's fillBufferAligned cost ~40us in-graph
//      for a 1.5KB fill — round 7 post-mortem; this costs ~2us) ----
__global__ __launch_bounds__(256) void zero_ints(int* __restrict__ p, int n) {
    int i = blockIdx.x * 256 + threadIdx.x;
    if (i < n) p[i] = 0;
}

// ---- Pass A1: per-bucket edge counts ----
__global__ __launch_bounds__(256) void bucket_count(const int* __restrict__ row,
                                                    int* __restrict__ bcnt,
                                                    int e, int nbk) {
    __shared__ int bh[512];
    int tid = threadIdx.x;
    for (int j = tid; j < nbk; j += 256) bh[j] = 0;
    __syncthreads();
    int base = blockIdx.x * EPB;
#pragma unroll
    for (int k = 0; k < EPB / 256; ++k) {
        int i = base + k * 256 + tid;
        if (i < e) atomicAdd(&bh[row[i] >> 8], 1);
    }
    __syncthreads();
    for (int j = tid; j < nbk; j += 256) {
        int c = bh[j];
        if (c) atomicAdd(&bcnt[j], c);
    }
}

// ---- Pass A2: scan bucket counts (single block) ----
__global__ __launch_bounds__(256) void bucket_scan(const int* __restrict__ bcnt,
                                                   int* __restrict__ bbase,
                                                   int* __restrict__ bcursor,
                                                   int* __restrict__ off,
                                                   int nbk, int n, int e) {
    __shared__ int sa[512], sb[512];
    int tid = threadIdx.x;
    for (int j = tid; j < 512; j += 256) sa[j] = (j < nbk) ? bcnt[j] : 0;
    __syncthreads();
    int* in = sa;
    int* out = sb;
    for (int d = 1; d < 512; d <<= 1) {
        for (int j = tid; j < 512; j += 256)
            out[j] = in[j] + ((j >= d) ? in[j - d] : 0);
        __syncthreads();
        int* t = in; in = out; out = t;
    }
    for (int j = tid; j < nbk; j += 256) {
        int incl = in[j];
        int excl = incl - bcnt[j];
        bbase[j] = excl;
        bcursor[j] = excl;
        if (j == nbk - 1) bbase[nbk] = incl;
    }
    if (tid == 0) off[n] = e;
}

// ---- Pass A3: scatter packed edges into bucket regions ----
__global__ __launch_bounds__(256) void bucket_scatter(const int* __restrict__ row,
                                                      const int* __restrict__ col,
                                                      int* __restrict__ bcursor,
                                                      int* __restrict__ packed,
                                                      int e, int nbk) {
    __shared__ int bh[512];
    __shared__ int bbase[512];
    __shared__ int bcur[512];
    int tid = threadIdx.x;
    for (int j = tid; j < nbk; j += 256) { bh[j] = 0; bcur[j] = 0; }
    __syncthreads();
    int base = blockIdx.x * EPB;
#pragma unroll
    for (int k = 0; k < EPB / 256; ++k) {
        int i = base + k * 256 + tid;
        if (i < e) atomicAdd(&bh[row[i] >> 8], 1);
    }
    __syncthreads();
    for (int j = tid; j < nbk; j += 256) {
        int c = bh[j];
        bbase[j] = c ? atomicAdd(&bcursor[j], c) : 0;
    }
    __syncthreads();
#pragma unroll
    for (int k = 0; k < EPB / 256; ++k) {
        int i = base + k * 256 + tid;
        if (i < e) {
            int r = row[i];
            int b = r >> 8;
            int slot = bbase[b] + atomicAdd(&bcur[b], 1);
            packed[slot] = ((r & 255) << 17) | col[i];
        }
    }
}

// ---- Pass B: per-bucket row histogram + scan -> off/dis/csr ----
__global__ __launch_bounds__(256) void bucket_build(const int* __restrict__ packed,
                                                    const int* __restrict__ bbase,
                                                    int* __restrict__ off,
                                                    float* __restrict__ dis,
                                                    int* __restrict__ csr, int n) {
    __shared__ int rcnt[256];
    __shared__ int sa[256], sb[256];
    int tid = threadIdx.x;
    int b = blockIdx.x;
    int ebase = bbase[b], eend = bbase[b + 1];
    rcnt[tid] = 0;
    __syncthreads();
    for (int e = ebase + tid; e < eend; e += 256)
        atomicAdd(&rcnt[packed[e] >> 17], 1);
    __syncthreads();
    sa[tid] = rcnt[tid];
    __syncthreads();
    int* in = sa;
    int* out = sb;
    for (int d = 1; d < 256; d <<= 1) {
        out[tid] = in[tid] + ((tid >= d) ? in[tid - d] : 0);
        __syncthreads();
        int* t = in; in = out; out = t;
    }
    // in[tid] = inclusive scan; out is free for reuse as cursor
    int grow = b * 256 + tid;
    int c = rcnt[tid];
    int excl = in[tid] - c;
    if (grow < n) {
        off[grow] = ebase + excl;
        dis[grow] = (c > 0) ? rsqrtf((float)c) : 0.0f;
    }
    out[tid] = excl;
    __syncthreads();
    for (int e = ebase + tid; e < eend; e += 256) {
        int p = packed[e];
        int lr = p >> 17;
        int pos = atomicAdd(&out[lr], 1);
        csr[ebase + pos] = p & 0x1FFFF;
    }
}

// ---------------- y = bf16(dis*x), xb = bf16(x) ----------------

__global__ __launch_bounds__(256) void scale_xy(const float* __restrict__ x,
                                                const float* __restrict__ dis,
                                                unsigned short* __restrict__ y,
                                                unsigned short* __restrict__ xb, int n) {
    int id = blockIdx.x * 256 + threadIdx.x;  // over N*16 quads
    if (id < n * 16) {
        int r = id >> 4;
        float d = dis[r];
        float4 v = ((const float4*)x)[id];
        ushort4 o = {f2bf(v.x * d), f2bf(v.y * d), f2bf(v.z * d), f2bf(v.w * d)};
        ((ushort4*)y)[id] = o;
        ushort4 xo = {f2bf(v.x), f2bf(v.y), f2bf(v.z), f2bf(v.w)};
        ((ushort4*)xb)[id] = xo;
    }
}

// ---------------- aggregate: tx[r][f] = bf16(-dis[r] * sum_e y[col][f]) ----------------
// thread = (row, feature-quad): 16 threads per row, 16 rows per block.
// y is bf16: 8 B gathered per lane per edge. 8-edge unroll for MLP depth
// (latency-bound gather: more outstanding loads per lane).

__global__ __launch_bounds__(256) void aggregate(const unsigned short* __restrict__ y,
                                                 const int* __restrict__ csr,
                                                 const int* __restrict__ off,
                                                 const float* __restrict__ dis,
                                                 unsigned short* __restrict__ tx, int n) {
    int tid = threadIdx.x;
    int r = blockIdx.x * 16 + (tid >> 4);
    if (r >= n) return;
    int q = tid & 15;
    int s0 = off[r], e1 = off[r + 1];
    const ushort4* Y = (const ushort4*)y;
    float ax = 0.f, ay = 0.f, az = 0.f, aw = 0.f;
    int t = s0;
    for (; t + 8 <= e1; t += 8) {
        int c0 = csr[t], c1 = csr[t + 1], c2 = csr[t + 2], c3 = csr[t + 3];
        int c4 = csr[t + 4], c5 = csr[t + 5], c6 = csr[t + 6], c7 = csr[t + 7];
        ushort4 v0 = Y[(size_t)c0 * 16 + q];
        ushort4 v1 = Y[(size_t)c1 * 16 + q];
        ushort4 v2 = Y[(size_t)c2 * 16 + q];
        ushort4 v3 = Y[(size_t)c3 * 16 + q];
        ushort4 v4 = Y[(size_t)c4 * 16 + q];
        ushort4 v5 = Y[(size_t)c5 * 16 + q];
        ushort4 v6 = Y[(size_t)c6 * 16 + q];
        ushort4 v7 = Y[(size_t)c7 * 16 + q];
        ax += ((bf2f(v0.x) + bf2f(v1.x)) + (bf2f(v2.x) + bf2f(v3.x))) +
              ((bf2f(v4.x) + bf2f(v5.x)) + (bf2f(v6.x) + bf2f(v7.x)));
        ay += ((bf2f(v0.y) + bf2f(v1.y)) + (bf2f(v2.y) + bf2f(v3.y))) +
              ((bf2f(v4.y) + bf2f(v5.y)) + (bf2f(v6.y) + bf2f(v7.y)));
        az += ((bf2f(v0.z) + bf2f(v1.z)) + (bf2f(v2.z) + bf2f(v3.z))) +
              ((bf2f(v4.z) + bf2f(v5.z)) + (bf2f(v6.z) + bf2f(v7.z)));
        aw += ((bf2f(v0.w) + bf2f(v1.w)) + (bf2f(v2.w) + bf2f(v3.w))) +
              ((bf2f(v4.w) + bf2f(v5.w)) + (bf2f(v6.w) + bf2f(v7.w)));
    }
    for (; t + 4 <= e1; t += 4) {
        int c0 = csr[t], c1 = csr[t + 1], c2 = csr[t + 2], c3 = csr[t + 3];
        ushort4 v0 = Y[(size_t)c0 * 16 + q];
        ushort4 v1 = Y[(size_t)c1 * 16 + q];
        ushort4 v2 = Y[(size_t)c2 * 16 + q];
        ushort4 v3 = Y[(size_t)c3 * 16 + q];
        ax += (bf2f(v0.x) + bf2f(v1.x)) + (bf2f(v2.x) + bf2f(v3.x));
        ay += (bf2f(v0.y) + bf2f(v1.y)) + (bf2f(v2.y) + bf2f(v3.y));
        az += (bf2f(v0.z) + bf2f(v1.z)) + (bf2f(v2.z) + bf2f(v3.z));
        aw += (bf2f(v0.w) + bf2f(v1.w)) + (bf2f(v2.w) + bf2f(v3.w));
    }
    for (; t < e1; ++t) {
        int c = csr[t];
        ushort4 v = Y[(size_t)c * 16 + q];
        ax += bf2f(v.x); ay += bf2f(v.y); az += bf2f(v.z); aw += bf2f(v.w);
    }
    float d = -dis[r];
    ushort4 o = {f2bf(ax * d), f2bf(ay * d), f2bf(az * d), f2bf(aw * d)};
    *(ushort4*)&tx[(size_t)r * 64 + q * 4] = o;
}

// ---------------- dense via MFMA ----------------
// out[N x NC] = act( [A0 | A1] (N x 128, bf16) @ [W0; W1] (128 x NC, fp32->bf16) + b )
// mfma_f32_16x16x32_bf16, one 16-row x NC tile per wave, grid-stride over row blocks.
// B-fragments (whole weight matrix) live in registers, loaded once per thread.
// k-slot labeling k = kt*32 + g*8 + i is identical for A and B loads (bijection cancels).
// D layout: col = lane&15, row = 4*(lane>>4)+reg  [verified m89/m91].

template <int NC, bool RELU, bool WRITE_HY>
__global__ __launch_bounds__(256) void dense_mfma(const unsigned short* __restrict__ A0,
                                                  const unsigned short* __restrict__ A1,
                                                  const float* __restrict__ W0,
                                                  const float* __restrict__ W1,
                                                  const float* __restrict__ bias,
                                                  const float* __restrict__ dis,
                                                  unsigned short* __restrict__ hout,
                                                  unsigned short* __restrict__ yout,
                                                  float* __restrict__ fout,
                                                  int n, int nrb) {
    constexpr int NT = NC / 16;
    int lane = threadIdx.x & 63;
    int m = lane & 15;   // A row / B col / D col within tile
    int g = lane >> 4;   // k-group
    bf16x8 bf[NT][4];
#pragma unroll
    for (int kt = 0; kt < 4; ++kt) {
        const float* W = (kt < 2) ? W0 : W1;
        int kb = (kt & 1) * 32 + g * 8;
#pragma unroll
        for (int nt = 0; nt < NT; ++nt) {
#pragma unroll
            for (int i = 0; i < 8; ++i)
                bf[nt][kt][i] = (short)f2bf(W[(kb + i) * NC + nt * 16 + m]);
        }
    }
    int wrb = blockIdx.x * 4 + (threadIdx.x >> 6);
    int stride = gridDim.x * 4;
    for (int rb = wrb; rb < nrb; rb += stride) {
        int r0 = rb * 16;
        int ra = r0 + m;
        if (ra > n - 1) ra = n - 1;  // clamped read; write is masked below
        const unsigned short* q0 = A0 + (size_t)ra * 64 + g * 8;
        const unsigned short* q1 = A1 + (size_t)ra * 64 + g * 8;
        bf16x8 a0 = *(const bf16x8*)q0;
        bf16x8 a1 = *(const bf16x8*)(q0 + 32);
        bf16x8 a2 = *(const bf16x8*)q1;
        bf16x8 a3 = *(const bf16x8*)(q1 + 32);
        f32x4 acc[NT];
#pragma unroll
        for (int nt = 0; nt < NT; ++nt) {
            float b = bias[nt * 16 + m];
            acc[nt][0] = b; acc[nt][1] = b; acc[nt][2] = b; acc[nt][3] = b;
        }
#pragma unroll
        for (int nt = 0; nt < NT; ++nt) {
            acc[nt] = __builtin_amdgcn_mfma_f32_16x16x32_bf16(a0, bf[nt][0], acc[nt], 0, 0, 0);
            acc[nt] = __builtin_amdgcn_mfma_f32_16x16x32_bf16(a1, bf[nt][1], acc[nt], 0, 0, 0);
            acc[nt] = __builtin_amdgcn_mfma_f32_16x16x32_bf16(a2, bf[nt][2], acc[nt], 0, 0, 0);
            acc[nt] = __builtin_amdgcn_mfma_f32_16x16x32_bf16(a3, bf[nt][3], acc[nt], 0, 0, 0);
        }
#pragma unroll
        for (int reg = 0; reg < 4; ++reg) {
            int rr = r0 + 4 * g + reg;
            if (rr >= n) continue;
            if (WRITE_HY) {
                float dv = dis[rr];
#pragma unroll
                for (int nt = 0; nt < NT; ++nt) {
                    float v = acc[nt][reg];
                    if (RELU) v = fmaxf(v, 0.f);
                    hout[(size_t)rr * NC + nt * 16 + m] = f2bf(v);
                    yout[(size_t)rr * NC + nt * 16 + m] = f2bf(v * dv);
                }
            } else {
#pragma unroll
                for (int nt = 0; nt < NT; ++nt)
                    fout[(size_t)rr * NC + nt * 16 + m] = acc[nt][reg];
            }
        }
    }
}

// ---------------- launch ----------------

extern "C" void kernel_launch(void* const* d_in, const int* in_sizes, int n_in,
                              void* d_out, int out_size, void* d_ws, size_t ws_size,
                              hipStream_t stream) {
    const float* x    = (const float*)d_in[0];
    const int*   adj  = (const int*)d_in[1];
    const float* W1_0 = (const float*)d_in[2];
    const float* W1_1 = (const float*)d_in[3];
    const float* b1   = (const float*)d_in[4];
    const float* Wx_0 = (const float*)d_in[5];
    const float* Wx_1 = (const float*)d_in[6];
    const float* bx   = (const float*)d_in[7];
    const float* W2_0 = (const float*)d_in[8];
    const float* W2_1 = (const float*)d_in[9];
    const float* b2   = (const float*)d_in[10];
    float* out = (float*)d_out;

    int N = in_sizes[0] / 64;
    int E = in_sizes[1] / 2;
    const int* row = adj;
    const int* col = adj + E;
    int NBK = (N + 255) / 256;  // rows bucketed by row>>8; requires N <= 131072
    int nRB = (N + 15) / 16;

    char* p = (char*)d_ws;
    auto alloc = [&](size_t bytes) {
        char* q = p;
        p += (bytes + 255) & ~(size_t)255;
        return q;
    };
    int*   bcnt  = (int*)alloc((size_t)(NBK) * 4);
    int*   bbase = (int*)alloc((size_t)(NBK + 1) * 4);
    int*   bcur  = (int*)alloc((size_t)(NBK) * 4);
    int*   off   = (int*)alloc((size_t)(N + 1) * 4);
    float* dis   = (float*)alloc((size_t)N * 4);
    int*   csr   = (int*)alloc((size_t)E * 4);
    unsigned short* y  = (unsigned short*)alloc((size_t)N * 64 * 2);
    unsigned short* xb = (unsigned short*)alloc((size_t)N * 64 * 2);
    unsigned short* tx = (unsigned short*)alloc((size_t)N * 64 * 2);
    unsigned short* h  = (unsigned short*)alloc((size_t)N * 64 * 2);
    (void)ws_size;
    int* packed = (int*)tx;  // reuse: packed edges (E*4 B) only live during CSR build

    int EB = (E + EPB - 1) / EPB;
    zero_ints<<<(NBK + 255) / 256, 256, 0, stream>>>(bcnt, NBK);
    bucket_count<<<EB, 256, 0, stream>>>(row, bcnt, E, NBK);
    bucket_scan<<<1, 256, 0, stream>>>(bcnt, bbase, bcur, off, NBK, N, E);
    bucket_scatter<<<EB, 256, 0, stream>>>(row, col, bcur, packed, E, NBK);
    bucket_build<<<NBK, 256, 0, stream>>>(packed, bbase, off, dis, csr, N);

    const int DG = 512;  // dense grid: 2048 waves, ~3 row-block iters each
    // layer 1
    scale_xy<<<(N * 16 + 255) / 256, 256, 0, stream>>>(x, dis, y, xb, N);
    aggregate<<<(N + 15) / 16, 256, 0, stream>>>(y, csr, off, dis, tx, N);
    dense_mfma<64, true, true><<<DG, 256, 0, stream>>>(xb, tx, W1_0, W1_1, b1, dis, h, y, nullptr, N, nRB);
    // layer x
    aggregate<<<(N + 15) / 16, 256, 0, stream>>>(y, csr, off, dis, tx, N);
    dense_mfma<64, true, true><<<DG, 256, 0, stream>>>(h, tx, Wx_0, Wx_1, bx, dis, h, y, nullptr, N, nRB);
    // layer 2
    aggregate<<<(N + 15) / 16, 256, 0, stream>>>(y, csr, off, dis, tx, N);
    dense_mfma<16, false, false><<<DG, 256, 0, stream>>>(h, tx, W2_0, W2_1, b2, dis, nullptr, nullptr, out, N, nRB);
}

// Round 9
// 202.656 us; speedup vs baseline: 6.5351x; 1.0042x over previous
//
#include <hip/hip_runtime.h>
#include <hip/hip_bf16.h>

// Two-level counting-sort CSR build:
//   bucket = row >> 8  (256 rows per bucket, NBK = ceil(N/256) <= 512 for N <= 131072)
//   packed edge record = (localrow << 17) | col   (needs N <= 2^17)

#define EPB 4096  // edges per block in bucket count/scatter

typedef __attribute__((ext_vector_type(8))) short bf16x8;
typedef __attribute__((ext_vector_type(4))) float f32x4;

__device__ __forceinline__ float bf2f(unsigned short u) {
    unsigned int x = ((unsigned int)u) << 16;
    return __uint_as_float(x);
}
__device__ __forceinline__ unsigned short f2bf(float f) {
    unsigned int b = __float_as_uint(f);
    unsigned int r = (b + 0x7FFF + ((b >> 16) & 1)) >> 16;  // round-nearest-even
    return (unsigned short)r;
}

// ---- tiny zero kernel (hipMemsetAsync's fillBufferAligned costs ~40us in-graph
//      for a 1.5KB fill — round 7 post-mortem; this costs ~2us) ----
__global__ __launch_bounds__(256) void zero_ints(int* __restrict__ p, int n) {
    int i = blockIdx.x * 256 + threadIdx.x;
    if (i < n) p[i] = 0;
}

// ---- one-shot weight convert+pack to MFMA fragment order ----
// packed idx = ((kt*NT + nt)*4 + g)*128 + m*8 + i
//   <-> source  k = (kt&1)*32 + g*8 + i (from W0 if kt<2 else W1), col = nt*16 + m
// Round-8 post-mortem: per-wave fp32 W load+cvt prologue (128 loads + 128 cvt
// per lane, x2048 waves = 64 MB L2 + 17M cvts) dominated dense_mfma; this
// kernel does the conversion once (18432 elements).
template <int NC>
__device__ __forceinline__ void pack_pair(const float* __restrict__ W0,
                                          const float* __restrict__ W1,
                                          unsigned short* __restrict__ out, int idx) {
    constexpr int NT = NC / 16;
    int i = idx & 7;
    int m = (idx >> 3) & 15;
    int g = (idx >> 7) & 3;
    int f = idx >> 9;  // kt*NT + nt
    int nt = f % NT;
    int kt = f / NT;
    const float* W = (kt < 2) ? W0 : W1;
    int k = (kt & 1) * 32 + g * 8 + i;
    out[idx] = f2bf(W[k * NC + nt * 16 + m]);
}

__global__ __launch_bounds__(256) void wconv_all(const float* __restrict__ W1_0,
                                                 const float* __restrict__ W1_1,
                                                 const float* __restrict__ Wx_0,
                                                 const float* __restrict__ Wx_1,
                                                 const float* __restrict__ W2_0,
                                                 const float* __restrict__ W2_1,
                                                 unsigned short* __restrict__ wp1,
                                                 unsigned short* __restrict__ wpx,
                                                 unsigned short* __restrict__ wp2) {
    int idx = blockIdx.x * 256 + threadIdx.x;
    if (idx < 8192) pack_pair<64>(W1_0, W1_1, wp1, idx);
    else if (idx < 16384) pack_pair<64>(Wx_0, Wx_1, wpx, idx - 8192);
    else if (idx < 18432) pack_pair<16>(W2_0, W2_1, wp2, idx - 16384);
}

// ---- Pass A1: per-bucket edge counts ----
__global__ __launch_bounds__(256) void bucket_count(const int* __restrict__ row,
                                                    int* __restrict__ bcnt,
                                                    int e, int nbk) {
    __shared__ int bh[512];
    int tid = threadIdx.x;
    for (int j = tid; j < nbk; j += 256) bh[j] = 0;
    __syncthreads();
    int base = blockIdx.x * EPB;
#pragma unroll
    for (int k = 0; k < EPB / 256; ++k) {
        int i = base + k * 256 + tid;
        if (i < e) atomicAdd(&bh[row[i] >> 8], 1);
    }
    __syncthreads();
    for (int j = tid; j < nbk; j += 256) {
        int c = bh[j];
        if (c) atomicAdd(&bcnt[j], c);
    }
}

// ---- Pass A2: scan bucket counts (single block) ----
__global__ __launch_bounds__(256) void bucket_scan(const int* __restrict__ bcnt,
                                                   int* __restrict__ bbase,
                                                   int* __restrict__ bcursor,
                                                   int* __restrict__ off,
                                                   int nbk, int n, int e) {
    __shared__ int sa[512], sb[512];
    int tid = threadIdx.x;
    for (int j = tid; j < 512; j += 256) sa[j] = (j < nbk) ? bcnt[j] : 0;
    __syncthreads();
    int* in = sa;
    int* out = sb;
    for (int d = 1; d < 512; d <<= 1) {
        for (int j = tid; j < 512; j += 256)
            out[j] = in[j] + ((j >= d) ? in[j - d] : 0);
        __syncthreads();
        int* t = in; in = out; out = t;
    }
    for (int j = tid; j < nbk; j += 256) {
        int incl = in[j];
        int excl = incl - bcnt[j];
        bbase[j] = excl;
        bcursor[j] = excl;
        if (j == nbk - 1) bbase[nbk] = incl;
    }
    if (tid == 0) off[n] = e;
}

// ---- Pass A3: scatter packed edges into bucket regions ----
__global__ __launch_bounds__(256) void bucket_scatter(const int* __restrict__ row,
                                                      const int* __restrict__ col,
                                                      int* __restrict__ bcursor,
                                                      int* __restrict__ packed,
                                                      int e, int nbk) {
    __shared__ int bh[512];
    __shared__ int bbase[512];
    __shared__ int bcur[512];
    int tid = threadIdx.x;
    for (int j = tid; j < nbk; j += 256) { bh[j] = 0; bcur[j] = 0; }
    __syncthreads();
    int base = blockIdx.x * EPB;
#pragma unroll
    for (int k = 0; k < EPB / 256; ++k) {
        int i = base + k * 256 + tid;
        if (i < e) atomicAdd(&bh[row[i] >> 8], 1);
    }
    __syncthreads();
    for (int j = tid; j < nbk; j += 256) {
        int c = bh[j];
        bbase[j] = c ? atomicAdd(&bcursor[j], c) : 0;
    }
    __syncthreads();
#pragma unroll
    for (int k = 0; k < EPB / 256; ++k) {
        int i = base + k * 256 + tid;
        if (i < e) {
            int r = row[i];
            int b = r >> 8;
            int slot = bbase[b] + atomicAdd(&bcur[b], 1);
            packed[slot] = ((r & 255) << 17) | col[i];
        }
    }
}

// ---- Pass B: per-bucket row histogram + scan -> off/dis/csr; fused y/xb scale ----
__global__ __launch_bounds__(256) void bucket_build(const int* __restrict__ packed,
                                                    const int* __restrict__ bbase,
                                                    const float* __restrict__ x,
                                                    int* __restrict__ off,
                                                    float* __restrict__ dis,
                                                    int* __restrict__ csr,
                                                    unsigned short* __restrict__ y,
                                                    unsigned short* __restrict__ xb,
                                                    int n) {
    __shared__ int rcnt[256];
    __shared__ int sa[256], sb[256];
    __shared__ float disv[256];
    int tid = threadIdx.x;
    int b = blockIdx.x;
    int ebase = bbase[b], eend = bbase[b + 1];
    rcnt[tid] = 0;
    __syncthreads();
    for (int e = ebase + tid; e < eend; e += 256)
        atomicAdd(&rcnt[packed[e] >> 17], 1);
    __syncthreads();
    sa[tid] = rcnt[tid];
    __syncthreads();
    int* in = sa;
    int* out = sb;
    for (int d = 1; d < 256; d <<= 1) {
        out[tid] = in[tid] + ((tid >= d) ? in[tid - d] : 0);
        __syncthreads();
        int* t = in; in = out; out = t;
    }
    // in[tid] = inclusive scan; out is free for reuse as cursor
    int grow = b * 256 + tid;
    int c = rcnt[tid];
    int excl = in[tid] - c;
    float dv = (c > 0) ? rsqrtf((float)c) : 0.0f;
    disv[tid] = dv;
    if (grow < n) {
        off[grow] = ebase + excl;
        dis[grow] = dv;
    }
    out[tid] = excl;
    __syncthreads();
    for (int e = ebase + tid; e < eend; e += 256) {
        int p = packed[e];
        int lr = p >> 17;
        int pos = atomicAdd(&out[lr], 1);
        csr[ebase + pos] = p & 0x1FFFF;
    }
    // fused scale pass: y = bf16(dis*x), xb = bf16(x) for this bucket's 256 rows
    for (int idx = tid; idx < 4096; idx += 256) {
        int rr = idx >> 4, q = idx & 15;
        int R = b * 256 + rr;
        if (R < n) {
            float d = disv[rr];
            float4 v = ((const float4*)x)[(size_t)R * 16 + q];
            ushort4 o = {f2bf(v.x * d), f2bf(v.y * d), f2bf(v.z * d), f2bf(v.w * d)};
            ((ushort4*)y)[(size_t)R * 16 + q] = o;
            ushort4 xo = {f2bf(v.x), f2bf(v.y), f2bf(v.z), f2bf(v.w)};
            ((ushort4*)xb)[(size_t)R * 16 + q] = xo;
        }
    }
}

// ---------------- aggregate: tx[r][f] = bf16(-dis[r] * sum_e y[col][f]) ----------------
// thread = (row, feature-quad): 16 threads per row, 16 rows per block.
// y is bf16: 8 B gathered per lane per edge. 8-edge unroll for MLP depth.

__global__ __launch_bounds__(256) void aggregate(const unsigned short* __restrict__ y,
                                                 const int* __restrict__ csr,
                                                 const int* __restrict__ off,
                                                 const float* __restrict__ dis,
                                                 unsigned short* __restrict__ tx, int n) {
    int tid = threadIdx.x;
    int r = blockIdx.x * 16 + (tid >> 4);
    if (r >= n) return;
    int q = tid & 15;
    int s0 = off[r], e1 = off[r + 1];
    const ushort4* Y = (const ushort4*)y;
    float ax = 0.f, ay = 0.f, az = 0.f, aw = 0.f;
    int t = s0;
    for (; t + 8 <= e1; t += 8) {
        int c0 = csr[t], c1 = csr[t + 1], c2 = csr[t + 2], c3 = csr[t + 3];
        int c4 = csr[t + 4], c5 = csr[t + 5], c6 = csr[t + 6], c7 = csr[t + 7];
        ushort4 v0 = Y[(size_t)c0 * 16 + q];
        ushort4 v1 = Y[(size_t)c1 * 16 + q];
        ushort4 v2 = Y[(size_t)c2 * 16 + q];
        ushort4 v3 = Y[(size_t)c3 * 16 + q];
        ushort4 v4 = Y[(size_t)c4 * 16 + q];
        ushort4 v5 = Y[(size_t)c5 * 16 + q];
        ushort4 v6 = Y[(size_t)c6 * 16 + q];
        ushort4 v7 = Y[(size_t)c7 * 16 + q];
        ax += ((bf2f(v0.x) + bf2f(v1.x)) + (bf2f(v2.x) + bf2f(v3.x))) +
              ((bf2f(v4.x) + bf2f(v5.x)) + (bf2f(v6.x) + bf2f(v7.x)));
        ay += ((bf2f(v0.y) + bf2f(v1.y)) + (bf2f(v2.y) + bf2f(v3.y))) +
              ((bf2f(v4.y) + bf2f(v5.y)) + (bf2f(v6.y) + bf2f(v7.y)));
        az += ((bf2f(v0.z) + bf2f(v1.z)) + (bf2f(v2.z) + bf2f(v3.z))) +
              ((bf2f(v4.z) + bf2f(v5.z)) + (bf2f(v6.z) + bf2f(v7.z)));
        aw += ((bf2f(v0.w) + bf2f(v1.w)) + (bf2f(v2.w) + bf2f(v3.w))) +
              ((bf2f(v4.w) + bf2f(v5.w)) + (bf2f(v6.w) + bf2f(v7.w)));
    }
    for (; t + 4 <= e1; t += 4) {
        int c0 = csr[t], c1 = csr[t + 1], c2 = csr[t + 2], c3 = csr[t + 3];
        ushort4 v0 = Y[(size_t)c0 * 16 + q];
        ushort4 v1 = Y[(size_t)c1 * 16 + q];
        ushort4 v2 = Y[(size_t)c2 * 16 + q];
        ushort4 v3 = Y[(size_t)c3 * 16 + q];
        ax += (bf2f(v0.x) + bf2f(v1.x)) + (bf2f(v2.x) + bf2f(v3.x));
        ay += (bf2f(v0.y) + bf2f(v1.y)) + (bf2f(v2.y) + bf2f(v3.y));
        az += (bf2f(v0.z) + bf2f(v1.z)) + (bf2f(v2.z) + bf2f(v3.z));
        aw += (bf2f(v0.w) + bf2f(v1.w)) + (bf2f(v2.w) + bf2f(v3.w));
    }
    for (; t < e1; ++t) {
        int c = csr[t];
        ushort4 v = Y[(size_t)c * 16 + q];
        ax += bf2f(v.x); ay += bf2f(v.y); az += bf2f(v.z); aw += bf2f(v.w);
    }
    float d = -dis[r];
    ushort4 o = {f2bf(ax * d), f2bf(ay * d), f2bf(az * d), f2bf(aw * d)};
    *(ushort4*)&tx[(size_t)r * 64 + q * 4] = o;
}

// ---------------- dense via MFMA ----------------
// out[N x NC] = act( [A0 | A1] (N x 128, bf16) @ Wp (pre-packed bf16 frags) + b )
// mfma_f32_16x16x32_bf16, one 16-row x NC tile per wave, grid-stride over row blocks.
// B fragments are pre-packed by wconv_all: lane (m,g) frag (nt,kt) is a single
// coalesced b128 load. No LDS, no barriers, no per-wave conversion.
// D layout: col = lane&15, row = 4*(lane>>4)+reg  [verified m89/m91].

template <int NC, bool RELU, bool WRITE_HY>
__global__ __launch_bounds__(256) void dense_mfma(const unsigned short* __restrict__ A0,
                                                  const unsigned short* __restrict__ A1,
                                                  const unsigned short* __restrict__ Wp,
                                                  const float* __restrict__ bias,
                                                  const float* __restrict__ dis,
                                                  unsigned short* __restrict__ hout,
                                                  unsigned short* __restrict__ yout,
                                                  float* __restrict__ fout,
                                                  int n, int nrb) {
    constexpr int NT = NC / 16;
    int lane = threadIdx.x & 63;
    int m = lane & 15;   // A row / B col / D col within tile
    int g = lane >> 4;   // k-group
    const bf16x8* WP = (const bf16x8*)Wp;
    bf16x8 bf[NT][4];
#pragma unroll
    for (int kt = 0; kt < 4; ++kt)
#pragma unroll
        for (int nt = 0; nt < NT; ++nt)
            bf[nt][kt] = WP[((kt * NT + nt) * 4 + g) * 16 + m];
    int wrb = blockIdx.x * 4 + (threadIdx.x >> 6);
    int stride = gridDim.x * 4;
    for (int rb = wrb; rb < nrb; rb += stride) {
        int r0 = rb * 16;
        int ra = r0 + m;
        if (ra > n - 1) ra = n - 1;  // clamped read; write is masked below
        const unsigned short* q0 = A0 + (size_t)ra * 64 + g * 8;
        const unsigned short* q1 = A1 + (size_t)ra * 64 + g * 8;
        bf16x8 a0 = *(const bf16x8*)q0;
        bf16x8 a1 = *(const bf16x8*)(q0 + 32);
        bf16x8 a2 = *(const bf16x8*)q1;
        bf16x8 a3 = *(const bf16x8*)(q1 + 32);
        f32x4 acc[NT];
#pragma unroll
        for (int nt = 0; nt < NT; ++nt) {
            float b = bias[nt * 16 + m];
            acc[nt][0] = b; acc[nt][1] = b; acc[nt][2] = b; acc[nt][3] = b;
        }
#pragma unroll
        for (int nt = 0; nt < NT; ++nt) {
            acc[nt] = __builtin_amdgcn_mfma_f32_16x16x32_bf16(a0, bf[nt][0], acc[nt], 0, 0, 0);
            acc[nt] = __builtin_amdgcn_mfma_f32_16x16x32_bf16(a1, bf[nt][1], acc[nt], 0, 0, 0);
            acc[nt] = __builtin_amdgcn_mfma_f32_16x16x32_bf16(a2, bf[nt][2], acc[nt], 0, 0, 0);
            acc[nt] = __builtin_amdgcn_mfma_f32_16x16x32_bf16(a3, bf[nt][3], acc[nt], 0, 0, 0);
        }
#pragma unroll
        for (int reg = 0; reg < 4; ++reg) {
            int rr = r0 + 4 * g + reg;
            if (rr >= n) continue;
            if (WRITE_HY) {
                float dv = dis[rr];
#pragma unroll
                for (int nt = 0; nt < NT; ++nt) {
                    float v = acc[nt][reg];
                    if (RELU) v = fmaxf(v, 0.f);
                    hout[(size_t)rr * NC + nt * 16 + m] = f2bf(v);
                    yout[(size_t)rr * NC + nt * 16 + m] = f2bf(v * dv);
                }
            } else {
#pragma unroll
                for (int nt = 0; nt < NT; ++nt)
                    fout[(size_t)rr * NC + nt * 16 + m] = acc[nt][reg];
            }
        }
    }
}

// ---------------- launch ----------------

extern "C" void kernel_launch(void* const* d_in, const int* in_sizes, int n_in,
                              void* d_out, int out_size, void* d_ws, size_t ws_size,
                              hipStream_t stream) {
    const float* x    = (const float*)d_in[0];
    const int*   adj  = (const int*)d_in[1];
    const float* W1_0 = (const float*)d_in[2];
    const float* W1_1 = (const float*)d_in[3];
    const float* b1   = (const float*)d_in[4];
    const float* Wx_0 = (const float*)d_in[5];
    const float* Wx_1 = (const float*)d_in[6];
    const float* bx   = (const float*)d_in[7];
    const float* W2_0 = (const float*)d_in[8];
    const float* W2_1 = (const float*)d_in[9];
    const float* b2   = (const float*)d_in[10];
    float* out = (float*)d_out;

    int N = in_sizes[0] / 64;
    int E = in_sizes[1] / 2;
    const int* row = adj;
    const int* col = adj + E;
    int NBK = (N + 255) / 256;  // rows bucketed by row>>8; requires N <= 131072
    int nRB = (N + 15) / 16;

    char* p = (char*)d_ws;
    auto alloc = [&](size_t bytes) {
        char* q = p;
        p += (bytes + 255) & ~(size_t)255;
        return q;
    };
    int*   bcnt  = (int*)alloc((size_t)(NBK) * 4);
    int*   bbase = (int*)alloc((size_t)(NBK + 1) * 4);
    int*   bcur  = (int*)alloc((size_t)(NBK) * 4);
    int*   off   = (int*)alloc((size_t)(N + 1) * 4);
    float* dis   = (float*)alloc((size_t)N * 4);
    int*   csr   = (int*)alloc((size_t)E * 4);
    unsigned short* wp1 = (unsigned short*)alloc(8192 * 2);
    unsigned short* wpx = (unsigned short*)alloc(8192 * 2);
    unsigned short* wp2 = (unsigned short*)alloc(2048 * 2);
    unsigned short* y  = (unsigned short*)alloc((size_t)N * 64 * 2);
    unsigned short* xb = (unsigned short*)alloc((size_t)N * 64 * 2);
    unsigned short* tx = (unsigned short*)alloc((size_t)N * 64 * 2);
    unsigned short* h  = (unsigned short*)alloc((size_t)N * 64 * 2);
    (void)ws_size;
    int* packed = (int*)tx;  // reuse: packed edges (E*4 B) only live during CSR build

    int EB = (E + EPB - 1) / EPB;
    zero_ints<<<(NBK + 255) / 256, 256, 0, stream>>>(bcnt, NBK);
    wconv_all<<<72, 256, 0, stream>>>(W1_0, W1_1, Wx_0, Wx_1, W2_0, W2_1, wp1, wpx, wp2);
    bucket_count<<<EB, 256, 0, stream>>>(row, bcnt, E, NBK);
    bucket_scan<<<1, 256, 0, stream>>>(bcnt, bbase, bcur, off, NBK, N, E);
    bucket_scatter<<<EB, 256, 0, stream>>>(row, col, bcur, packed, E, NBK);
    bucket_build<<<NBK, 256, 0, stream>>>(packed, bbase, x, off, dis, csr, y, xb, N);

    const int DG = 512;  // dense grid: 2048 waves, ~3 row-block iters each
    // layer 1
    aggregate<<<(N + 15) / 16, 256, 0, stream>>>(y, csr, off, dis, tx, N);
    dense_mfma<64, true, true><<<DG, 256, 0, stream>>>(xb, tx, wp1, b1, dis, h, y, nullptr, N, nRB);
    // layer x
    aggregate<<<(N + 15) / 16, 256, 0, stream>>>(y, csr, off, dis, tx, N);
    dense_mfma<64, true, true><<<DG, 256, 0, stream>>>(h, tx, wpx, bx, dis, h, y, nullptr, N, nRB);
    // layer 2
    aggregate<<<(N + 15) / 16, 256, 0, stream>>>(y, csr, off, dis, tx, N);
    dense_mfma<16, false, false><<<DG, 256, 0, stream>>>(h, tx, wp2, b2, dis, nullptr, nullptr, out, N, nRB);
}

// Round 11
// 188.331 us; speedup vs baseline: 7.0321x; 1.0761x over previous
//
#include <hip/hip_runtime.h>
#include <hip/hip_bf16.h>

// Two-level counting-sort CSR build:
//   bucket = row >> 8  (256 rows per bucket, NBK = ceil(N/256) <= 512 for N <= 131072)
//   packed edge record = (localrow << 17) | col   (needs N <= 2^17)

#define EPB 4096  // edges per block in bucket count/scatter

typedef __attribute__((ext_vector_type(8))) short bf16x8;
typedef __attribute__((ext_vector_type(4))) float f32x4;

__device__ __forceinline__ float bf2f(unsigned short u) {
    unsigned int x = ((unsigned int)u) << 16;
    return __uint_as_float(x);
}
__device__ __forceinline__ unsigned short f2bf(float f) {
    unsigned int b = __float_as_uint(f);
    unsigned int r = (b + 0x7FFF + ((b >> 16) & 1)) >> 16;  // round-nearest-even
    return (unsigned short)r;
}
__device__ __forceinline__ void acc8(float* a, bf16x8 v) {
#pragma unroll
    for (int i = 0; i < 8; ++i) a[i] += bf2f((unsigned short)(short)v[i]);
}

// ---- one-shot weight convert+pack to MFMA fragment order (+ bcnt zeroing) ----
// packed idx = ((kt*NT + nt)*4 + g)*128 + m*8 + i
//   <-> source  k = (kt&1)*32 + g*8 + i (from W0 if kt<2 else W1), col = nt*16 + m
template <int NC>
__device__ __forceinline__ void pack_pair(const float* __restrict__ W0,
                                          const float* __restrict__ W1,
                                          unsigned short* __restrict__ out, int idx) {
    constexpr int NT = NC / 16;
    int i = idx & 7;
    int m = (idx >> 3) & 15;
    int g = (idx >> 7) & 3;
    int f = idx >> 9;  // kt*NT + nt
    int nt = f % NT;
    int kt = f / NT;
    const float* W = (kt < 2) ? W0 : W1;
    int k = (kt & 1) * 32 + g * 8 + i;
    out[idx] = f2bf(W[k * NC + nt * 16 + m]);
}

__global__ __launch_bounds__(256) void wconv_all(const float* __restrict__ W1_0,
                                                 const float* __restrict__ W1_1,
                                                 const float* __restrict__ Wx_0,
                                                 const float* __restrict__ Wx_1,
                                                 const float* __restrict__ W2_0,
                                                 const float* __restrict__ W2_1,
                                                 unsigned short* __restrict__ wp1,
                                                 unsigned short* __restrict__ wpx,
                                                 unsigned short* __restrict__ wp2,
                                                 int* __restrict__ bcnt, int nbk) {
    int idx = blockIdx.x * 256 + threadIdx.x;
    if (idx < nbk) bcnt[idx] = 0;
    if (idx < 8192) pack_pair<64>(W1_0, W1_1, wp1, idx);
    else if (idx < 16384) pack_pair<64>(Wx_0, Wx_1, wpx, idx - 8192);
    else if (idx < 18432) pack_pair<16>(W2_0, W2_1, wp2, idx - 16384);
}

// ---- Pass A1: per-bucket edge counts ----
__global__ __launch_bounds__(256) void bucket_count(const int* __restrict__ row,
                                                    int* __restrict__ bcnt,
                                                    int e, int nbk) {
    __shared__ int bh[512];
    int tid = threadIdx.x;
    for (int j = tid; j < nbk; j += 256) bh[j] = 0;
    __syncthreads();
    int base = blockIdx.x * EPB;
#pragma unroll
    for (int k = 0; k < EPB / 256; ++k) {
        int i = base + k * 256 + tid;
        if (i < e) atomicAdd(&bh[row[i] >> 8], 1);
    }
    __syncthreads();
    for (int j = tid; j < nbk; j += 256) {
        int c = bh[j];
        if (c) atomicAdd(&bcnt[j], c);
    }
}

// ---- Pass A2: scan bucket counts (single block) ----
__global__ __launch_bounds__(256) void bucket_scan(const int* __restrict__ bcnt,
                                                   int* __restrict__ bbase,
                                                   int* __restrict__ bcursor,
                                                   int* __restrict__ off,
                                                   int nbk, int n, int e) {
    __shared__ int sa[512], sb[512];
    int tid = threadIdx.x;
    for (int j = tid; j < 512; j += 256) sa[j] = (j < nbk) ? bcnt[j] : 0;
    __syncthreads();
    int* in = sa;
    int* out = sb;
    for (int d = 1; d < 512; d <<= 1) {
        for (int j = tid; j < 512; j += 256)
            out[j] = in[j] + ((j >= d) ? in[j - d] : 0);
        __syncthreads();
        int* t = in; in = out; out = t;
    }
    for (int j = tid; j < nbk; j += 256) {
        int incl = in[j];
        int excl = incl - bcnt[j];
        bbase[j] = excl;
        bcursor[j] = excl;
        if (j == nbk - 1) bbase[nbk] = incl;
    }
    if (tid == 0) off[n] = e;
}

// ---- Pass A3: scatter packed edges into bucket regions ----
__global__ __launch_bounds__(256) void bucket_scatter(const int* __restrict__ row,
                                                      const int* __restrict__ col,
                                                      int* __restrict__ bcursor,
                                                      int* __restrict__ packed,
                                                      int e, int nbk) {
    __shared__ int bh[512];
    __shared__ int bbase[512];
    __shared__ int bcur[512];
    int tid = threadIdx.x;
    for (int j = tid; j < nbk; j += 256) { bh[j] = 0; bcur[j] = 0; }
    __syncthreads();
    int base = blockIdx.x * EPB;
#pragma unroll
    for (int k = 0; k < EPB / 256; ++k) {
        int i = base + k * 256 + tid;
        if (i < e) atomicAdd(&bh[row[i] >> 8], 1);
    }
    __syncthreads();
    for (int j = tid; j < nbk; j += 256) {
        int c = bh[j];
        bbase[j] = c ? atomicAdd(&bcursor[j], c) : 0;
    }
    __syncthreads();
#pragma unroll
    for (int k = 0; k < EPB / 256; ++k) {
        int i = base + k * 256 + tid;
        if (i < e) {
            int r = row[i];
            int b = r >> 8;
            int slot = bbase[b] + atomicAdd(&bcur[b], 1);
            packed[slot] = ((r & 255) << 17) | col[i];
        }
    }
}

// ---- Pass B: per-bucket row histogram + scan -> off/dis/csr; fused y/xb scale ----
__global__ __launch_bounds__(256) void bucket_build(const int* __restrict__ packed,
                                                    const int* __restrict__ bbase,
                                                    const float* __restrict__ x,
                                                    int* __restrict__ off,
                                                    float* __restrict__ dis,
                                                    int* __restrict__ csr,
                                                    unsigned short* __restrict__ y,
                                                    unsigned short* __restrict__ xb,
                                                    int n) {
    __shared__ int rcnt[256];
    __shared__ int sa[256], sb[256];
    __shared__ float disv[256];
    int tid = threadIdx.x;
    int b = blockIdx.x;
    int ebase = bbase[b], eend = bbase[b + 1];
    rcnt[tid] = 0;
    __syncthreads();
    for (int e = ebase + tid; e < eend; e += 256)
        atomicAdd(&rcnt[packed[e] >> 17], 1);
    __syncthreads();
    sa[tid] = rcnt[tid];
    __syncthreads();
    int* in = sa;
    int* out = sb;
    for (int d = 1; d < 256; d <<= 1) {
        out[tid] = in[tid] + ((tid >= d) ? in[tid - d] : 0);
        __syncthreads();
        int* t = in; in = out; out = t;
    }
    // in[tid] = inclusive scan; out is free for reuse as cursor
    int grow = b * 256 + tid;
    int c = rcnt[tid];
    int excl = in[tid] - c;
    float dv = (c > 0) ? rsqrtf((float)c) : 0.0f;
    disv[tid] = dv;
    if (grow < n) {
        off[grow] = ebase + excl;
        dis[grow] = dv;
    }
    out[tid] = excl;
    __syncthreads();
    for (int e = ebase + tid; e < eend; e += 256) {
        int p = packed[e];
        int lr = p >> 17;
        int pos = atomicAdd(&out[lr], 1);
        csr[ebase + pos] = p & 0x1FFFF;
    }
    // fused scale pass: y = bf16(dis*x), xb = bf16(x) for this bucket's 256 rows
    for (int idx = tid; idx < 4096; idx += 256) {
        int rr = idx >> 4, q = idx & 15;
        int R = b * 256 + rr;
        if (R < n) {
            float d = disv[rr];
            float4 v = ((const float4*)x)[(size_t)R * 16 + q];
            ushort4 o = {f2bf(v.x * d), f2bf(v.y * d), f2bf(v.z * d), f2bf(v.w * d)};
            ((ushort4*)y)[(size_t)R * 16 + q] = o;
            ushort4 xo = {f2bf(v.x), f2bf(v.y), f2bf(v.z), f2bf(v.w)};
            ((ushort4*)xb)[(size_t)R * 16 + q] = xo;
        }
    }
}

// ---------------- fused aggregate + dense ----------------
// Phase 1: 64 rows/block, 4 threads/row gather 16 feats each from y[col] (bf16),
//          fp32-accumulate, scale by -dis[r], store bf16 tx tile to LDS
//          (XOR-swizzled in 16B units: byte ^= (row&7)<<4 — kills the 16-way
//          bank conflict on phase-2's stride-128B ds_read_b128).
// Phase 2: 4 waves x 16-row MFMA tiles (the round-7-verified mapping):
//          A halves from global A0 (k 0..63) and LDS tx (k 64..127),
//          B frags pre-packed by wconv_all, D: col=lane&15, row=4*(lane>>4)+reg.
// Eliminates the tx global round-trip and one dispatch per layer.

template <int NC, bool RELU, bool WRITE_HY>
__global__ __launch_bounds__(256) void agg_dense(const unsigned short* __restrict__ y,
                                                 const unsigned short* __restrict__ A0,
                                                 const int* __restrict__ csr,
                                                 const int* __restrict__ off,
                                                 const float* __restrict__ dis,
                                                 const unsigned short* __restrict__ Wp,
                                                 const float* __restrict__ bias,
                                                 unsigned short* __restrict__ hout,
                                                 unsigned short* __restrict__ yout,
                                                 float* __restrict__ fout,
                                                 int n) {
    constexpr int NT = NC / 16;
    __shared__ unsigned short txl[64 * 64];  // 8 KB, [row][col] bf16, swizzled
    int tid = threadIdx.x;

    // ---- phase 1: gather ----
    int row_l = tid >> 2;  // 0..63
    int fq = tid & 3;      // 16-feature quarter
    int r = blockIdx.x * 64 + row_l;
    float acc16[16];
#pragma unroll
    for (int i = 0; i < 16; ++i) acc16[i] = 0.f;
    float d = 0.f;
    if (r < n) {
        int s0 = off[r], e1 = off[r + 1];
        const unsigned short* Yb = y + fq * 16;
        int t = s0;
        for (; t + 4 <= e1; t += 4) {
            int c0 = csr[t], c1 = csr[t + 1], c2 = csr[t + 2], c3 = csr[t + 3];
            const bf16x8* p0 = (const bf16x8*)(Yb + (size_t)c0 * 64);
            const bf16x8* p1 = (const bf16x8*)(Yb + (size_t)c1 * 64);
            const bf16x8* p2 = (const bf16x8*)(Yb + (size_t)c2 * 64);
            const bf16x8* p3 = (const bf16x8*)(Yb + (size_t)c3 * 64);
            bf16x8 v00 = p0[0], v01 = p0[1];
            bf16x8 v10 = p1[0], v11 = p1[1];
            bf16x8 v20 = p2[0], v21 = p2[1];
            bf16x8 v30 = p3[0], v31 = p3[1];
            acc8(acc16, v00); acc8(acc16 + 8, v01);
            acc8(acc16, v10); acc8(acc16 + 8, v11);
            acc8(acc16, v20); acc8(acc16 + 8, v21);
            acc8(acc16, v30); acc8(acc16 + 8, v31);
        }
        for (; t < e1; ++t) {
            int c = csr[t];
            const bf16x8* pc = (const bf16x8*)(Yb + (size_t)c * 64);
            bf16x8 v0 = pc[0], v1 = pc[1];
            acc8(acc16, v0); acc8(acc16 + 8, v1);
        }
        d = -dis[r];
    }
    bf16x8 ov0, ov1;
#pragma unroll
    for (int i = 0; i < 8; ++i) {
        ov0[i] = (short)f2bf(acc16[i] * d);
        ov1[i] = (short)f2bf(acc16[8 + i] * d);
    }
    int swz = (row_l & 7) << 4;
    int cb = fq * 32;
    *(bf16x8*)((char*)txl + row_l * 128 + (cb ^ swz)) = ov0;
    *(bf16x8*)((char*)txl + row_l * 128 + ((cb + 16) ^ swz)) = ov1;
    __syncthreads();

    // ---- phase 2: MFMA ----
    int lane = tid & 63;
    int m = lane & 15;
    int g = lane >> 4;
    int w = tid >> 6;
    const bf16x8* WP = (const bf16x8*)Wp;
    bf16x8 bf[NT][4];
#pragma unroll
    for (int kt = 0; kt < 4; ++kt)
#pragma unroll
        for (int nt = 0; nt < NT; ++nt)
            bf[nt][kt] = WP[((kt * NT + nt) * 4 + g) * 16 + m];
    int r0 = blockIdx.x * 64 + w * 16;
    int ra = r0 + m;
    if (ra > n - 1) ra = n - 1;  // clamped read; write masked below
    const unsigned short* q0 = A0 + (size_t)ra * 64 + g * 8;
    bf16x8 a0 = *(const bf16x8*)q0;
    bf16x8 a1 = *(const bf16x8*)(q0 + 32);
    int rl2 = w * 16 + m;  // rl2 & 7 == m & 7 (w*16 is a multiple of 16)
    int sw2 = (m & 7) << 4;
    bf16x8 a2 = *(bf16x8*)((char*)txl + rl2 * 128 + ((g * 16) ^ sw2));
    bf16x8 a3 = *(bf16x8*)((char*)txl + rl2 * 128 + ((64 + g * 16) ^ sw2));
    f32x4 acc[NT];
#pragma unroll
    for (int nt = 0; nt < NT; ++nt) {
        float b = bias[nt * 16 + m];
        acc[nt][0] = b; acc[nt][1] = b; acc[nt][2] = b; acc[nt][3] = b;
    }
#pragma unroll
    for (int nt = 0; nt < NT; ++nt) {
        acc[nt] = __builtin_amdgcn_mfma_f32_16x16x32_bf16(a0, bf[nt][0], acc[nt], 0, 0, 0);
        acc[nt] = __builtin_amdgcn_mfma_f32_16x16x32_bf16(a1, bf[nt][1], acc[nt], 0, 0, 0);
        acc[nt] = __builtin_amdgcn_mfma_f32_16x16x32_bf16(a2, bf[nt][2], acc[nt], 0, 0, 0);
        acc[nt] = __builtin_amdgcn_mfma_f32_16x16x32_bf16(a3, bf[nt][3], acc[nt], 0, 0, 0);
    }
#pragma unroll
    for (int reg = 0; reg < 4; ++reg) {
        int rr = r0 + 4 * g + reg;
        if (rr >= n) continue;
        if (WRITE_HY) {
            float dv = dis[rr];
#pragma unroll
            for (int nt = 0; nt < NT; ++nt) {
                float v = acc[nt][reg];
                if (RELU) v = fmaxf(v, 0.f);
                hout[(size_t)rr * NC + nt * 16 + m] = f2bf(v);
                yout[(size_t)rr * NC + nt * 16 + m] = f2bf(v * dv);
            }
        } else {
#pragma unroll
            for (int nt = 0; nt < NT; ++nt)
                fout[(size_t)rr * NC + nt * 16 + m] = acc[nt][reg];
        }
    }
}

// ---------------- launch ----------------

extern "C" void kernel_launch(void* const* d_in, const int* in_sizes, int n_in,
                              void* d_out, int out_size, void* d_ws, size_t ws_size,
                              hipStream_t stream) {
    const float* x    = (const float*)d_in[0];
    const int*   adj  = (const int*)d_in[1];
    const float* W1_0 = (const float*)d_in[2];
    const float* W1_1 = (const float*)d_in[3];
    const float* b1   = (const float*)d_in[4];
    const float* Wx_0 = (const float*)d_in[5];
    const float* Wx_1 = (const float*)d_in[6];
    const float* bx   = (const float*)d_in[7];
    const float* W2_0 = (const float*)d_in[8];
    const float* W2_1 = (const float*)d_in[9];
    const float* b2   = (const float*)d_in[10];
    float* out = (float*)d_out;

    int N = in_sizes[0] / 64;
    int E = in_sizes[1] / 2;
    const int* row = adj;
    const int* col = adj + E;
    int NBK = (N + 255) / 256;  // rows bucketed by row>>8; requires N <= 131072

    char* p = (char*)d_ws;
    auto alloc = [&](size_t bytes) {
        char* q = p;
        p += (bytes + 255) & ~(size_t)255;
        return q;
    };
    int*   bcnt  = (int*)alloc((size_t)(NBK) * 4);
    int*   bbase = (int*)alloc((size_t)(NBK + 1) * 4);
    int*   bcur  = (int*)alloc((size_t)(NBK) * 4);
    int*   off   = (int*)alloc((size_t)(N + 1) * 4);
    float* dis   = (float*)alloc((size_t)N * 4);
    int*   csr   = (int*)alloc((size_t)E * 4);
    int*   packed = (int*)alloc((size_t)E * 4);
    unsigned short* wp1 = (unsigned short*)alloc(8192 * 2);
    unsigned short* wpx = (unsigned short*)alloc(8192 * 2);
    unsigned short* wp2 = (unsigned short*)alloc(2048 * 2);
    unsigned short* y  = (unsigned short*)alloc((size_t)N * 64 * 2);
    unsigned short* y2 = (unsigned short*)alloc((size_t)N * 64 * 2);
    unsigned short* xb = (unsigned short*)alloc((size_t)N * 64 * 2);
    unsigned short* h  = (unsigned short*)alloc((size_t)N * 64 * 2);
    unsigned short* h2 = (unsigned short*)alloc((size_t)N * 64 * 2);
    (void)ws_size;

    int EB = (E + EPB - 1) / EPB;
    wconv_all<<<72, 256, 0, stream>>>(W1_0, W1_1, Wx_0, Wx_1, W2_0, W2_1,
                                      wp1, wpx, wp2, bcnt, NBK);
    bucket_count<<<EB, 256, 0, stream>>>(row, bcnt, E, NBK);
    bucket_scan<<<1, 256, 0, stream>>>(bcnt, bbase, bcur, off, NBK, N, E);
    bucket_scatter<<<EB, 256, 0, stream>>>(row, col, bcur, packed, E, NBK);
    bucket_build<<<NBK, 256, 0, stream>>>(packed, bbase, x, off, dis, csr, y, xb, N);

    int nb64 = (N + 63) / 64;
    // layer 1: gather from y, dense on [xb | tx] -> h, next-layer y2
    agg_dense<64, true, true><<<nb64, 256, 0, stream>>>(y, xb, csr, off, dis, wp1, b1, h, y2, nullptr, N);
    // layer x: gather from y2, dense on [h | tx] -> h2, next-layer y
    agg_dense<64, true, true><<<nb64, 256, 0, stream>>>(y2, h, csr, off, dis, wpx, bx, h2, y, nullptr, N);
    // layer 2: gather from y, dense on [h2 | tx] -> out (fp32)
    agg_dense<16, false, false><<<nb64, 256, 0, stream>>>(y, h2, csr, off, dis, wp2, b2, nullptr, nullptr, out, N);
}